// Round 14
// baseline (1486.403 us; speedup 1.0000x reference)
//
#include <hip/hip_runtime.h>

// MSDeformAttn Transformer encoder (Deformable-DETR), MI355X.
// Round 14: revert hgemmln to r12 2-phase + move A-fragments out of LDS into
//           registers (even/odd named dbuf, static indices). LDS = B-only
//           32 KB; per-iter LDS traffic -30%. Rest identical to r12.

constexpr int kB  = 2;
constexpr int kD  = 256;
constexpr int kNH = 8;
constexpr int kLV = 4;
constexpr int kNP = 4;
constexpr int kNL = 6;
constexpr int kDFF = 1024;
constexpr int kS  = 16660;                 // 112^2+56^2+28^2+14^2
constexpr int kM  = kB * kS;               // 33320
constexpr int kMp = 33408;                 // 261*128 (padded rows)
constexpr int kMT64 = kMp / 64;            // 522

typedef short bf16x8 __attribute__((ext_vector_type(8)));
typedef float f32x4  __attribute__((ext_vector_type(4)));

__device__ __forceinline__ unsigned short f2bf(float x) {
  union { float f; unsigned int u; } v; v.f = x;
  unsigned int r = v.u + 0x7FFFu + ((v.u >> 16) & 1u);
  return (unsigned short)(r >> 16);
}
__device__ __forceinline__ float bf2f(unsigned short u) {
  union { unsigned int u; float f; } v; v.u = ((unsigned int)u) << 16;
  return v.f;
}
__device__ __forceinline__ float bflo(unsigned int u) {
  union { unsigned int u; float f; } v; v.u = u << 16;
  return v.f;
}
__device__ __forceinline__ float bfhi(unsigned int u) {
  union { unsigned int u; float f; } v; v.u = u & 0xFFFF0000u;
  return v.f;
}

#define GLOAD_LDS16(gp, lp)                                                    \
  __builtin_amdgcn_global_load_lds(                                            \
      (const __attribute__((address_space(1))) void*)(gp),                     \
      (__attribute__((address_space(3))) void*)(lp), 16, 0, 0)

#define SBARRIER() asm volatile("s_barrier" ::: "memory")

// ---------------------------------------------------------------------------
// Input flatten+transpose; emits x fp32, x bf16, q=x+pos bf16, pos bf16.
// ---------------------------------------------------------------------------
__global__ __launch_bounds__(256) void build_xpos_k(
    const float* __restrict__ src, const float* __restrict__ pos,
    const float* __restrict__ lemb, float* __restrict__ xout,
    unsigned short* __restrict__ posbf, unsigned short* __restrict__ xbf,
    unsigned short* __restrict__ qbf, int HW, int s0, int lvl)
{
  __shared__ float ts[32][33];
  __shared__ float tp[32][33];
  const int b  = blockIdx.z;
  const int p0 = blockIdx.x * 32, d0 = blockIdx.y * 32;
  const int tx = threadIdx.x, ty = threadIdx.y;   // (32, 8)
  for (int dd = ty; dd < 32; dd += 8) {
    int p = p0 + tx;
    if (p < HW) {
      size_t idx = ((size_t)b * kD + (d0 + dd)) * (size_t)HW + p;
      ts[dd][tx] = src[idx];
      tp[dd][tx] = pos[idx];
    }
  }
  __syncthreads();
  for (int pp = ty; pp < 32; pp += 8) {
    int p = p0 + pp, d = d0 + tx;
    if (p < HW) {
      size_t o = ((size_t)b * kS + (s0 + p)) * (size_t)kD + d;
      float x = ts[tx][pp];
      float pv = tp[tx][pp] + lemb[lvl * kD + d];
      xout[o] = x;
      posbf[o] = f2bf(pv);
      xbf[o] = f2bf(x);
      qbf[o] = f2bf(x + pv);
    }
  }
}

// ---------------------------------------------------------------------------
// Weight convert+transpose: W fp32 [NL][K][N] -> Wt bf16 [NL][rows][K] at rowoff
// ---------------------------------------------------------------------------
__global__ __launch_bounds__(256) void wconv_k(
    const float* __restrict__ W, unsigned short* __restrict__ Wt,
    int K, int N, int rowoff, int rowstotal)
{
  __shared__ float t[32][33];
  const int l = blockIdx.z;
  const int n0 = blockIdx.x * 32, k0 = blockIdx.y * 32;
  const int tx = threadIdx.x & 31, ty = threadIdx.x >> 5;
  const float* Wl = W + (size_t)l * K * N;
  unsigned short* Wtl = Wt + (size_t)l * rowstotal * K;
  for (int kk = ty; kk < 32; kk += 8)
    t[kk][tx] = Wl[(size_t)(k0 + kk) * N + n0 + tx];
  __syncthreads();
  for (int nn = ty; nn < 32; nn += 8)
    Wtl[(size_t)(rowoff + n0 + nn) * K + k0 + tx] = f2bf(t[tx][nn]);
}

__global__ __launch_bounds__(256) void biaspack_k(
    const float* __restrict__ ob, const float* __restrict__ ab,
    float* __restrict__ qb)
{
  int i = blockIdx.x * 256 + threadIdx.x;
  if (i >= kNL * 384) return;
  int l = i / 384, c = i - l * 384;
  qb[i] = (c < 256) ? ob[l * 256 + c] : ab[l * 128 + (c - 256)];
}

// ---------------------------------------------------------------------------
// Reference-point table: ref[s] = (rx, ry) in [0,1], once per call.
// ---------------------------------------------------------------------------
__global__ __launch_bounds__(256) void refxy_k(float* __restrict__ ref)
{
  int s = blockIdx.x * 256 + threadIdx.x;
  if (s >= kS) return;
  int ls, side;
  if (s < 12544)      { ls = s;         side = 112; }
  else if (s < 15680) { ls = s - 12544; side = 56;  }
  else if (s < 16464) { ls = s - 15680; side = 28;  }
  else                { ls = s - 16464; side = 14;  }
  const float inv = 1.0f / (float)side;
  ref[s * 2 + 0] = ((ls % side) + 0.5f) * inv;
  ref[s * 2 + 1] = ((ls / side) + 0.5f) * inv;
}

// ---------------------------------------------------------------------------
// bf16 MFMA GEMM, BM=64/BN=128: 256 threads, 4 waves 2x2 of 32x64,
// depth-2 counted-vmcnt pipeline. Used for ff1.
// ---------------------------------------------------------------------------
template<int RELU, int OUTBF>
__global__ __launch_bounds__(256) void hgemm64_k(
    const unsigned short* __restrict__ A, const unsigned short* __restrict__ Bt,
    const float* __restrict__ bias, void* __restrict__ Cout, int N, int K)
{
  __shared__ unsigned short As[2][64 * 32];    // 2x4 KB
  __shared__ unsigned short Bs[2][128 * 32];   // 2x8 KB
  const int tid = threadIdx.x;
  const int bm = blockIdx.y * 64;
  const int bn = blockIdx.x * 128;
  const int lane = tid & 63;
  const int wave = tid >> 6;
  const int wr = (wave >> 1) * 32, wc = (wave & 1) * 64;
  const int l15 = lane & 15, l4 = lane >> 4;

  f32x4 acc[2][4] = {};

  const unsigned short* A0 = A + (size_t)(bm + (tid >> 2)) * K + ((tid & 3) << 3);
  const int cb1 = 256 + tid;
  const unsigned short* B0 = Bt + (size_t)(bn + (tid >> 2)) * K + ((tid & 3) << 3);
  const unsigned short* B1 = Bt + (size_t)(bn + (cb1 >> 2)) * K + ((cb1 & 3) << 3);

#define STAGE64(buf, k0)                                                       \
  do {                                                                         \
    GLOAD_LDS16(A0 + (k0), (char*)As[buf] + tid * 16);                         \
    GLOAD_LDS16(B0 + (k0), (char*)Bs[buf] + tid * 16);                         \
    GLOAD_LDS16(B1 + (k0), (char*)Bs[buf] + cb1 * 16);                         \
  } while (0)

  const int nt = K >> 5;
  STAGE64(0, 0);
  STAGE64(1, 32);
  for (int k = 0; k < nt; ++k) {
    if (k + 1 < nt) asm volatile("s_waitcnt vmcnt(3)" ::: "memory");
    else            asm volatile("s_waitcnt vmcnt(0)" ::: "memory");
    SBARRIER();
    __builtin_amdgcn_sched_barrier(0);
    const int cur = k & 1;
    bf16x8 af[2], bfr[4];
#pragma unroll
    for (int m = 0; m < 2; ++m)
      af[m] = *(const bf16x8*)&As[cur][(wr + m * 16 + l15) * 32 + l4 * 8];
#pragma unroll
    for (int n = 0; n < 4; ++n)
      bfr[n] = *(const bf16x8*)&Bs[cur][(wc + n * 16 + l15) * 32 + l4 * 8];
#pragma unroll
    for (int m = 0; m < 2; ++m)
#pragma unroll
      for (int n = 0; n < 4; ++n)
        acc[m][n] = __builtin_amdgcn_mfma_f32_16x16x32_bf16(
            af[m], bfr[n], acc[m][n], 0, 0, 0);
    SBARRIER();
    if (k + 2 < nt) STAGE64(cur, (k + 2) * 32);
  }
#undef STAGE64

#pragma unroll
  for (int n = 0; n < 4; ++n) {
    const int col = bn + wc + n * 16 + l15;
    const float bv = bias[col];
#pragma unroll
    for (int m = 0; m < 2; ++m) {
#pragma unroll
      for (int j = 0; j < 4; ++j) {
        const int row = bm + wr + m * 16 + l4 * 4 + j;
        float v = acc[m][n][j] + bv;
        if (RELU) v = fmaxf(v, 0.f);
        if (OUTBF)
          ((unsigned short*)Cout)[(size_t)row * N + col] = f2bf(v);
        else
          ((float*)Cout)[(size_t)row * N + col] = v;
      }
    }
  }
}

// ---------------------------------------------------------------------------
// Merged qout+val GEMM: grid (5, kMT64). bx<3: qout = (x+pos)@qw + qbias
// (N=384, fp16 out); bx>=3: val = x@vw + vbias (N=256, bf16 out). K=256.
// ---------------------------------------------------------------------------
__global__ __launch_bounds__(256) void qvgemm_k(
    const unsigned short* __restrict__ Aq, const unsigned short* __restrict__ Ax,
    const unsigned short* __restrict__ Bq, const unsigned short* __restrict__ Bv,
    const float* __restrict__ biasq, const float* __restrict__ biasv,
    _Float16* __restrict__ Cq, unsigned short* __restrict__ Cv)
{
  constexpr int K = 256;
  __shared__ unsigned short As[2][64 * 32];
  __shared__ unsigned short Bs[2][128 * 32];
  const int tid = threadIdx.x;
  const int bx = blockIdx.x;           // 0..4
  const bool isv = bx >= 3;
  const int bn = (isv ? bx - 3 : bx) * 128;
  const int bm = blockIdx.y * 64;
  const unsigned short* A  = isv ? Ax : Aq;
  const unsigned short* Bt = isv ? Bv : Bq;
  const float* bias = isv ? biasv : biasq;
  const int lane = tid & 63;
  const int wave = tid >> 6;
  const int wr = (wave >> 1) * 32, wc = (wave & 1) * 64;
  const int l15 = lane & 15, l4 = lane >> 4;

  f32x4 acc[2][4] = {};

  const unsigned short* A0 = A + (size_t)(bm + (tid >> 2)) * K + ((tid & 3) << 3);
  const int cb1 = 256 + tid;
  const unsigned short* B0 = Bt + (size_t)(bn + (tid >> 2)) * K + ((tid & 3) << 3);
  const unsigned short* B1 = Bt + (size_t)(bn + (cb1 >> 2)) * K + ((cb1 & 3) << 3);

#define STAGEQV(buf, k0)                                                       \
  do {                                                                         \
    GLOAD_LDS16(A0 + (k0), (char*)As[buf] + tid * 16);                         \
    GLOAD_LDS16(B0 + (k0), (char*)Bs[buf] + tid * 16);                         \
    GLOAD_LDS16(B1 + (k0), (char*)Bs[buf] + cb1 * 16);                         \
  } while (0)

  const int nt = K >> 5;               // 8
  STAGEQV(0, 0);
  STAGEQV(1, 32);
  for (int k = 0; k < nt; ++k) {
    if (k + 1 < nt) asm volatile("s_waitcnt vmcnt(3)" ::: "memory");
    else            asm volatile("s_waitcnt vmcnt(0)" ::: "memory");
    SBARRIER();
    __builtin_amdgcn_sched_barrier(0);
    const int cur = k & 1;
    bf16x8 af[2], bfr[4];
#pragma unroll
    for (int m = 0; m < 2; ++m)
      af[m] = *(const bf16x8*)&As[cur][(wr + m * 16 + l15) * 32 + l4 * 8];
#pragma unroll
    for (int n = 0; n < 4; ++n)
      bfr[n] = *(const bf16x8*)&Bs[cur][(wc + n * 16 + l15) * 32 + l4 * 8];
#pragma unroll
    for (int m = 0; m < 2; ++m)
#pragma unroll
      for (int n = 0; n < 4; ++n)
        acc[m][n] = __builtin_amdgcn_mfma_f32_16x16x32_bf16(
            af[m], bfr[n], acc[m][n], 0, 0, 0);
    SBARRIER();
    if (k + 2 < nt) STAGEQV(cur, (k + 2) * 32);
  }
#undef STAGEQV

#pragma unroll
  for (int n = 0; n < 4; ++n) {
    const int col = bn + wc + n * 16 + l15;
    const float bv = bias[col];
#pragma unroll
    for (int m = 0; m < 2; ++m) {
#pragma unroll
      for (int j = 0; j < 4; ++j) {
        const int row = bm + wr + m * 16 + l4 * 4 + j;
        float v = acc[m][n][j] + bv;
        if (isv)
          Cv[(size_t)row * 256 + col] = f2bf(v);
        else
          Cq[(size_t)row * 384 + col] = (_Float16)v;
      }
    }
  }
}

// ---------------------------------------------------------------------------
// bf16 MFMA GEMM with fused bias+residual+LayerNorm epilogue.
// BM=64, BN=256, 512 threads (8 waves 2Mx4N of 32x64), BK=32.
// B staged in LDS (2x16 KB); A-fragments loaded DIRECTLY into registers
// (even/odd named dbuf, loop step 2 -> all indices static). 4 vm-ops/iter
// (2 B-gloads + 2 A-loads) -> steady vmcnt(4), drain at last iter.
// ---------------------------------------------------------------------------
template<int WQ, int OUTDST>
__global__ __launch_bounds__(512) void hgemmln_k(
    const unsigned short* __restrict__ A, const unsigned short* __restrict__ Bt,
    const float* __restrict__ bias, const float* __restrict__ Rsd,
    const float* __restrict__ g, const float* __restrict__ beta,
    const unsigned short* __restrict__ posbf, float* __restrict__ yout,
    unsigned short* __restrict__ xbf, unsigned short* __restrict__ qbf, int K)
{
  __shared__ unsigned short Bs[2][256 * 32];   // 2 x 16 KB
  __shared__ float ssum[64][5];
  __shared__ float ssq[64][5];
  const int tid = threadIdx.x;
  const int bm = blockIdx.x * 64;
  const int lane = tid & 63;
  const int wave = tid >> 6;          // 0..7
  const int wm = wave >> 2;           // 0..1
  const int wn = wave & 3;            // 0..3
  const int wc = wn * 64;
  const int l15 = lane & 15, l4 = lane >> 4;

  f32x4 acc[2][4] = {};

  // B staging: 1024 chunks, 2/thread
  const unsigned short* Bq0 = Bt + (size_t)(tid >> 2) * K + ((tid & 3) << 3);
  const unsigned short* Bq1 = Bt + (size_t)(128 + (tid >> 2)) * K + ((tid & 3) << 3);
  // A fragments per lane: rows bm+wm*32+{0,16}+l15, k = l4*8
  const unsigned short* A0p = A + (size_t)(bm + wm * 32 + l15) * K + l4 * 8;
  const unsigned short* A1p = A0p + (size_t)16 * K;

#define STB(buf, k0)                                                           \
  do {                                                                         \
    GLOAD_LDS16(Bq0 + (k0), (char*)Bs[buf] + tid * 16);                        \
    GLOAD_LDS16(Bq1 + (k0), (char*)Bs[buf] + (512 + tid) * 16);                \
  } while (0)

#define COMPUTE(buf, aa0, aa1)                                                 \
  do {                                                                         \
    bf16x8 b0 = *(const bf16x8*)&Bs[buf][(wc + 0 * 16 + l15) * 32 + l4 * 8];   \
    bf16x8 b1 = *(const bf16x8*)&Bs[buf][(wc + 1 * 16 + l15) * 32 + l4 * 8];   \
    bf16x8 b2 = *(const bf16x8*)&Bs[buf][(wc + 2 * 16 + l15) * 32 + l4 * 8];   \
    bf16x8 b3 = *(const bf16x8*)&Bs[buf][(wc + 3 * 16 + l15) * 32 + l4 * 8];   \
    acc[0][0] = __builtin_amdgcn_mfma_f32_16x16x32_bf16(aa0, b0, acc[0][0], 0, 0, 0); \
    acc[1][0] = __builtin_amdgcn_mfma_f32_16x16x32_bf16(aa1, b0, acc[1][0], 0, 0, 0); \
    acc[0][1] = __builtin_amdgcn_mfma_f32_16x16x32_bf16(aa0, b1, acc[0][1], 0, 0, 0); \
    acc[1][1] = __builtin_amdgcn_mfma_f32_16x16x32_bf16(aa1, b1, acc[1][1], 0, 0, 0); \
    acc[0][2] = __builtin_amdgcn_mfma_f32_16x16x32_bf16(aa0, b2, acc[0][2], 0, 0, 0); \
    acc[1][2] = __builtin_amdgcn_mfma_f32_16x16x32_bf16(aa1, b2, acc[1][2], 0, 0, 0); \
    acc[0][3] = __builtin_amdgcn_mfma_f32_16x16x32_bf16(aa0, b3, acc[0][3], 0, 0, 0); \
    acc[1][3] = __builtin_amdgcn_mfma_f32_16x16x32_bf16(aa1, b3, acc[1][3], 0, 0, 0); \
  } while (0)

  const int nt = K >> 5;               // 8 or 32 (even)
  bf16x8 aE0, aE1, aO0, aO1;

  // Prologue: B(0), A(0), B(1), A(1)  -> 8 outstanding vm ops
  STB(0, 0);
  aE0 = *(const bf16x8*)(A0p + 0);
  aE1 = *(const bf16x8*)(A1p + 0);
  STB(1, 32);
  aO0 = *(const bf16x8*)(A0p + 32);
  aO1 = *(const bf16x8*)(A1p + 32);

  for (int k = 0; k < nt; k += 2) {
    // ---- even iteration: buffer 0, frags aE*
    if (k + 1 < nt) asm volatile("s_waitcnt vmcnt(4)" ::: "memory");
    else            asm volatile("s_waitcnt vmcnt(0)" ::: "memory");
    SBARRIER();
    __builtin_amdgcn_sched_barrier(0);
    COMPUTE(0, aE0, aE1);
    SBARRIER();
    if (k + 2 < nt) {
      STB(0, (k + 2) * 32);
      aE0 = *(const bf16x8*)(A0p + (k + 2) * 32);
      aE1 = *(const bf16x8*)(A1p + (k + 2) * 32);
    }
    // ---- odd iteration: buffer 1, frags aO*
    if (k + 2 < nt) asm volatile("s_waitcnt vmcnt(4)" ::: "memory");
    else            asm volatile("s_waitcnt vmcnt(0)" ::: "memory");
    SBARRIER();
    __builtin_amdgcn_sched_barrier(0);
    COMPUTE(1, aO0, aO1);
    SBARRIER();
    if (k + 3 < nt) {
      STB(1, (k + 3) * 32);
      aO0 = *(const bf16x8*)(A0p + (k + 3) * 32);
      aO1 = *(const bf16x8*)(A1p + (k + 3) * 32);
    }
  }
#undef STB
#undef COMPUTE

  // ---- epilogue: bias + residual + LayerNorm
  float bv[4], gv[4], btv[4];
#pragma unroll
  for (int n = 0; n < 4; ++n) {
    const int col = wc + n * 16 + l15;
    bv[n] = bias[col];
    gv[n] = g[col];
    btv[n] = beta[col];
  }
#pragma unroll
  for (int m = 0; m < 2; ++m) {
#pragma unroll
    for (int j = 0; j < 4; ++j) {
      const int row = bm + wm * 32 + m * 16 + l4 * 4 + j;
#pragma unroll
      for (int n = 0; n < 4; ++n)
        acc[m][n][j] += bv[n] + Rsd[(size_t)row * kD + wc + n * 16 + l15];
    }
  }
#pragma unroll
  for (int m = 0; m < 2; ++m) {
#pragma unroll
    for (int j = 0; j < 4; ++j) {
      float s = acc[m][0][j] + acc[m][1][j] + acc[m][2][j] + acc[m][3][j];
      float q = acc[m][0][j] * acc[m][0][j] + acc[m][1][j] * acc[m][1][j] +
                acc[m][2][j] * acc[m][2][j] + acc[m][3][j] * acc[m][3][j];
#pragma unroll
      for (int d2 = 1; d2 < 16; d2 <<= 1) {
        s += __shfl_xor(s, d2, 64);
        q += __shfl_xor(q, d2, 64);
      }
      if (l15 == 0) {
        const int r = wm * 32 + m * 16 + l4 * 4 + j;
        ssum[r][wn] = s;
        ssq[r][wn] = q;
      }
    }
  }
  __syncthreads();
#pragma unroll
  for (int m = 0; m < 2; ++m) {
#pragma unroll
    for (int j = 0; j < 4; ++j) {
      const int r = wm * 32 + m * 16 + l4 * 4 + j;
      const int row = bm + r;
      const float mean = (ssum[r][0] + ssum[r][1] + ssum[r][2] + ssum[r][3]) *
                         (1.0f / kD);
      const float var = (ssq[r][0] + ssq[r][1] + ssq[r][2] + ssq[r][3]) *
                        (1.0f / kD) - mean * mean;
      const float rstd = rsqrtf(var + 1e-5f);
      if (row < kM) {
#pragma unroll
        for (int n = 0; n < 4; ++n) {
          const int col = wc + n * 16 + l15;
          const float y = (acc[m][n][j] - mean) * rstd * gv[n] + btv[n];
          const size_t o = (size_t)row * kD + col;
          if (OUTDST) {
            yout[o] = y;
          } else {
            yout[o] = y;
            xbf[o] = f2bf(y);
            if (WQ) qbf[o] = f2bf(y + bf2f(posbf[o]));
          }
        }
      }
    }
  }
}

// ---------------------------------------------------------------------------
// MS deformable attention sampling (+fused softmax), 8 queries per block,
// XCD-bijective block swizzle.
// ---------------------------------------------------------------------------
__global__ __launch_bounds__(256) void msdeform_k(
    const unsigned short* __restrict__ val, const _Float16* __restrict__ qout,
    const float* __restrict__ ref, unsigned short* __restrict__ outbf)
{
  __shared__ int   sIdx[4][8][128];   // [corner][q][sp*8+h] byte offsets
  __shared__ float sW[4][8][128];
  // bijective XCD swizzle (m204): nwg = kM/8 = 4165, q8 = 520, r8 = 5
  const int bid = blockIdx.x;
  const int xcd = bid & 7;
  const int jj  = bid >> 3;
  const int wg  = (xcd < 5 ? xcd * 521 : 5 * 521 + (xcd - 5) * 520) + jj;
  const int bs0 = wg * 8;
  const int tid = threadIdx.x;

#pragma unroll
  for (int it = 0; it < 4; ++it) {
    const int item = tid + it * 256;
    const int q = item >> 7;         // 0..7
    const int t = item & 127;        // h*16 + l*4 + p
    const int bs = bs0 + q;
    const int b = bs / kS, s = bs - b * kS;
    const int l = (t & 15) >> 2;

    const float logit = (float)qout[(size_t)bs * 384 + 256 + t];
    float mx = logit;
#pragma unroll
    for (int d2 = 1; d2 < 16; d2 <<= 1) mx = fmaxf(mx, __shfl_xor(mx, d2, 64));
    float e = __expf(logit - mx);
    float sm = e;
#pragma unroll
    for (int d2 = 1; d2 < 16; d2 <<= 1) sm += __shfl_xor(sm, d2, 64);
    const float a = e / sm;

    const float rfx = ref[s * 2 + 0];
    const float rfy = ref[s * 2 + 1];
    const int side  = 112 >> l;
    const int start = (l >= 1 ? 12544 : 0) + (l >= 2 ? 3136 : 0) + (l >= 3 ? 784 : 0);
    const float ox = (float)qout[(size_t)bs * 384 + t * 2 + 0];
    const float oy = (float)qout[(size_t)bs * 384 + t * 2 + 1];
    const float xx = fmaf(rfx, (float)side, ox) - 0.5f;
    const float yy = fmaf(rfy, (float)side, oy) - 0.5f;
    const float xf = floorf(xx), yf = floorf(yy);
    const float lx = xx - xf, ly = yy - yf;
    const int x0 = (int)xf, y0 = (int)yf;
    const float w00 = (1.f - lx) * (1.f - ly) * a, w10 = lx * (1.f - ly) * a;
    const float w01 = (1.f - lx) * ly * a,         w11 = lx * ly * a;
    const bool xv0 = (unsigned)x0 < (unsigned)side, xv1 = (unsigned)(x0 + 1) < (unsigned)side;
    const bool yv0 = (unsigned)y0 < (unsigned)side, yv1 = (unsigned)(y0 + 1) < (unsigned)side;
    const int cx0 = min(max(x0, 0), side - 1), cx1 = min(max(x0 + 1, 0), side - 1);
    const int cy0 = min(max(y0, 0), side - 1), cy1 = min(max(y0 + 1, 0), side - 1);
    const int rowbase = b * kS + start;
    const int t2 = (t & 15) * 8 + (t >> 4);   // sp*8 + h
    sIdx[0][q][t2] = (rowbase + cy0 * side + cx0) << 9;   // *512 B/row (bf16)
    sIdx[1][q][t2] = (rowbase + cy0 * side + cx1) << 9;
    sIdx[2][q][t2] = (rowbase + cy1 * side + cx0) << 9;
    sIdx[3][q][t2] = (rowbase + cy1 * side + cx1) << 9;
    sW[0][q][t2] = (xv0 && yv0) ? w00 : 0.f;
    sW[1][q][t2] = (xv1 && yv0) ? w10 : 0.f;
    sW[2][q][t2] = (xv0 && yv1) ? w01 : 0.f;
    sW[3][q][t2] = (xv1 && yv1) ? w11 : 0.f;
  }
  __syncthreads();

  const int q  = tid >> 5;            // 0..7 (2 queries per wave)
  const int h  = (tid >> 2) & 7;      // 0..7
  const int l4 = tid & 3;             // 0..3 (16B = 8 bf16 sub-row)
  const char* vbase = (const char*)val + h * 64 + l4 * 16;

  float a0 = 0.f, a1 = 0.f, a2 = 0.f, a3 = 0.f;
  float a4 = 0.f, a5 = 0.f, a6 = 0.f, a7 = 0.f;
#pragma unroll
  for (int sp = 0; sp < 16; ++sp) {
    const int t2 = sp * 8 + h;
#pragma unroll
    for (int c = 0; c < 4; ++c) {
      const int off = sIdx[c][q][t2];
      const float w = sW[c][q][t2];
      const uint4 v = *(const uint4*)(vbase + off);
      a0 = fmaf(w, bflo(v.x), a0); a1 = fmaf(w, bfhi(v.x), a1);
      a2 = fmaf(w, bflo(v.y), a2); a3 = fmaf(w, bfhi(v.y), a3);
      a4 = fmaf(w, bflo(v.z), a4); a5 = fmaf(w, bfhi(v.z), a5);
      a6 = fmaf(w, bflo(v.w), a6); a7 = fmaf(w, bfhi(v.w), a7);
    }
  }
  bf16x8 o;
  o[0] = (short)f2bf(a0); o[1] = (short)f2bf(a1);
  o[2] = (short)f2bf(a2); o[3] = (short)f2bf(a3);
  o[4] = (short)f2bf(a4); o[5] = (short)f2bf(a5);
  o[6] = (short)f2bf(a6); o[7] = (short)f2bf(a7);
  *(bf16x8*)(outbf + (size_t)(bs0 + q) * 256 + h * 32 + l4 * 8) = o;
}

// ---------------------------------------------------------------------------
__global__ void tail_k(float* __restrict__ out)
{
  if (threadIdx.x == 0) {
    const size_t n = (size_t)kM * kD;
    out[n + 0] = 112.f; out[n + 1] = 112.f;
    out[n + 2] = 56.f;  out[n + 3] = 56.f;
    out[n + 4] = 28.f;  out[n + 5] = 28.f;
    out[n + 6] = 14.f;  out[n + 7] = 14.f;
    out[n + 8] = 0.f;   out[n + 9] = 12544.f;
    out[n + 10] = 15680.f; out[n + 11] = 16464.f;
  }
}

// ---------------------------------------------------------------------------
extern "C" void kernel_launch(void* const* d_in, const int* in_sizes, int n_in,
                              void* d_out, int out_size, void* d_ws, size_t ws_size,
                              hipStream_t stream)
{
  const float* src[4] = {(const float*)d_in[0], (const float*)d_in[2],
                         (const float*)d_in[4], (const float*)d_in[6]};
  const float* pos[4] = {(const float*)d_in[1], (const float*)d_in[3],
                         (const float*)d_in[5], (const float*)d_in[7]};
  const float* lemb  = (const float*)d_in[8];
  const float* off_w = (const float*)d_in[9];
  const float* off_b = (const float*)d_in[10];
  const float* aw_w  = (const float*)d_in[11];
  const float* aw_b  = (const float*)d_in[12];
  const float* val_w = (const float*)d_in[13];
  const float* val_b = (const float*)d_in[14];
  const float* out_w = (const float*)d_in[15];
  const float* out_b = (const float*)d_in[16];
  const float* ln1_s = (const float*)d_in[17];
  const float* ln1_b = (const float*)d_in[18];
  const float* ff1_w = (const float*)d_in[19];
  const float* ff1_b = (const float*)d_in[20];
  const float* ff2_w = (const float*)d_in[21];
  const float* ff2_b = (const float*)d_in[22];
  const float* ln2_s = (const float*)d_in[23];
  const float* ln2_b = (const float*)d_in[24];

  const size_t SZ = (size_t)kMp * kD;      // 8,552,448 floats
  float* ws   = (float*)d_ws;
  float* xb   = ws;                                   // fp32 [SZ]
  _Float16* qoutH = (_Float16*)(ws + SZ);             // [Mp][384] = 0.75 SZ
  unsigned short* valbf = (unsigned short*)(ws + SZ + (3 * SZ) / 4); // 0.5 SZ
  unsigned short* attbf = valbf + SZ;                 // 0.5 SZ
  unsigned short* ffbf  = (unsigned short*)(ws + SZ); // [Mp][1024], aliases ^
  unsigned short* posbf = (unsigned short*)(ws + 3 * SZ);      // 0.5 SZ
  unsigned short* qbf   = posbf + SZ;                          // 0.5 SZ
  unsigned short* xbf   = qbf + SZ;                            // 0.5 SZ
  unsigned short* wts   = (unsigned short*)(ws + 4 * SZ + SZ / 2);
  unsigned short* qwT  = wts;                    // [NL][384][256]
  unsigned short* valT = qwT + kNL * 384 * 256;  // [NL][256][256]
  unsigned short* outT = valT + kNL * 256 * 256;
  unsigned short* ff1T = outT + kNL * 256 * 256; // [NL][1024][256]
  unsigned short* ff2T = ff1T + kNL * 1024 * 256;// [NL][256][1024]
  float* qbias = (float*)(ff2T + kNL * 256 * 1024); // [NL][384]
  float* reftab = qbias + kNL * 384;                // [kS][2]

  // --- weight prep + ref table ---
  wconv_k<<<dim3(256 / 32, 256 / 32, kNL), 256, 0, stream>>>(off_w, qwT, 256, 256, 0, 384);
  wconv_k<<<dim3(128 / 32, 256 / 32, kNL), 256, 0, stream>>>(aw_w,  qwT, 256, 128, 256, 384);
  wconv_k<<<dim3(256 / 32, 256 / 32, kNL), 256, 0, stream>>>(val_w, valT, 256, 256, 0, 256);
  wconv_k<<<dim3(256 / 32, 256 / 32, kNL), 256, 0, stream>>>(out_w, outT, 256, 256, 0, 256);
  wconv_k<<<dim3(1024 / 32, 256 / 32, kNL), 256, 0, stream>>>(ff1_w, ff1T, 256, 1024, 0, 1024);
  wconv_k<<<dim3(256 / 32, 1024 / 32, kNL), 256, 0, stream>>>(ff2_w, ff2T, 1024, 256, 0, 256);
  biaspack_k<<<(kNL * 384 + 255) / 256, 256, 0, stream>>>(off_b, aw_b, qbias);
  refxy_k<<<(kS + 255) / 256, 256, 0, stream>>>(reftab);

  // --- build x0, bf16 copies ---
  const int sides[4]  = {112, 56, 28, 14};
  const int starts[4] = {0, 12544, 15680, 16464};
  for (int l = 0; l < 4; ++l) {
    int HW = sides[l] * sides[l];
    dim3 g((HW + 31) / 32, kD / 32, kB);
    build_xpos_k<<<g, dim3(32, 8), 0, stream>>>(src[l], pos[l], lemb, xb, posbf,
                                                xbf, qbf, HW, starts[l], l);
  }

  const dim3 blk(256);
  for (int i = 0; i < kNL; ++i) {
    // qout = (x+pos) @ [off_w|aw_w] + qbias (fp16)  AND  val = x @ val_w + b
    qvgemm_k<<<dim3(5, kMT64), blk, 0, stream>>>(
        qbf, xbf, qwT + (size_t)i * 384 * 256, valT + (size_t)i * 256 * 256,
        qbias + i * 384, val_b + i * 256, qoutH, valbf);
    // sampling (+softmax fused)
    msdeform_k<<<kM / 8, blk, 0, stream>>>(valbf, qoutH, reftab, attbf);
    // x = LN1(x + attn @ out_w + out_b)  [fused]
    hgemmln_k<0, 0><<<kMT64, 512, 0, stream>>>(
        attbf, outT + (size_t)i * 256 * 256, out_b + i * 256, xb,
        ln1_s + i * kD, ln1_b + i * kD, nullptr, xb, xbf, nullptr, 256);
    // ffmid = relu(x @ ff1_w + ff1_b) -> bf16
    hgemm64_k<1, 1><<<dim3(8, kMT64), blk, 0, stream>>>(
        xbf, ff1T + (size_t)i * 1024 * 256, ff1_b + i * 1024, ffbf, 1024, 256);
    // x = LN2(x + ffmid @ ff2_w + ff2_b)  [fused; last layer -> d_out]
    if (i < kNL - 1) {
      hgemmln_k<1, 0><<<kMT64, 512, 0, stream>>>(
          ffbf, ff2T + (size_t)i * 256 * 1024, ff2_b + i * 256, xb,
          ln2_s + i * kD, ln2_b + i * kD, posbf, xb, xbf, qbf, 1024);
    } else {
      hgemmln_k<0, 1><<<kMT64, 512, 0, stream>>>(
          ffbf, ff2T + (size_t)i * 256 * 1024, ff2_b + i * 256, xb,
          ln2_s + i * kD, ln2_b + i * kD, nullptr, (float*)d_out, nullptr,
          nullptr, 1024);
    }
  }

  tail_k<<<1, 64, 0, stream>>>((float*)d_out);
}

// Round 15
// 1294.965 us; speedup vs baseline: 1.1478x; 1.1478x over previous
//
#include <hip/hip_runtime.h>

// MSDeformAttn Transformer encoder (Deformable-DETR), MI355X.
// Round 15: r12 structure, but the residual stream x is bf16-ONLY:
//           hgemmln reads Rsd bf16 and writes xbf/qbf (no fp32 x state);
//           last layer writes d_out fp32 directly. ~-27% LN-GEMM traffic.

constexpr int kB  = 2;
constexpr int kD  = 256;
constexpr int kNH = 8;
constexpr int kLV = 4;
constexpr int kNP = 4;
constexpr int kNL = 6;
constexpr int kDFF = 1024;
constexpr int kS  = 16660;                 // 112^2+56^2+28^2+14^2
constexpr int kM  = kB * kS;               // 33320
constexpr int kMp = 33408;                 // 261*128 (padded rows)
constexpr int kMT64 = kMp / 64;            // 522

typedef short bf16x8 __attribute__((ext_vector_type(8)));
typedef float f32x4  __attribute__((ext_vector_type(4)));

__device__ __forceinline__ unsigned short f2bf(float x) {
  union { float f; unsigned int u; } v; v.f = x;
  unsigned int r = v.u + 0x7FFFu + ((v.u >> 16) & 1u);
  return (unsigned short)(r >> 16);
}
__device__ __forceinline__ float bf2f(unsigned short u) {
  union { unsigned int u; float f; } v; v.u = ((unsigned int)u) << 16;
  return v.f;
}
__device__ __forceinline__ float bflo(unsigned int u) {
  union { unsigned int u; float f; } v; v.u = u << 16;
  return v.f;
}
__device__ __forceinline__ float bfhi(unsigned int u) {
  union { unsigned int u; float f; } v; v.u = u & 0xFFFF0000u;
  return v.f;
}

#define GLOAD_LDS16(gp, lp)                                                    \
  __builtin_amdgcn_global_load_lds(                                            \
      (const __attribute__((address_space(1))) void*)(gp),                     \
      (__attribute__((address_space(3))) void*)(lp), 16, 0, 0)

#define SBARRIER() asm volatile("s_barrier" ::: "memory")

// ---------------------------------------------------------------------------
// Input flatten+transpose; emits x bf16, q=x+pos bf16, pos bf16.
// ---------------------------------------------------------------------------
__global__ __launch_bounds__(256) void build_xpos_k(
    const float* __restrict__ src, const float* __restrict__ pos,
    const float* __restrict__ lemb, unsigned short* __restrict__ posbf,
    unsigned short* __restrict__ xbf, unsigned short* __restrict__ qbf,
    int HW, int s0, int lvl)
{
  __shared__ float ts[32][33];
  __shared__ float tp[32][33];
  const int b  = blockIdx.z;
  const int p0 = blockIdx.x * 32, d0 = blockIdx.y * 32;
  const int tx = threadIdx.x, ty = threadIdx.y;   // (32, 8)
  for (int dd = ty; dd < 32; dd += 8) {
    int p = p0 + tx;
    if (p < HW) {
      size_t idx = ((size_t)b * kD + (d0 + dd)) * (size_t)HW + p;
      ts[dd][tx] = src[idx];
      tp[dd][tx] = pos[idx];
    }
  }
  __syncthreads();
  for (int pp = ty; pp < 32; pp += 8) {
    int p = p0 + pp, d = d0 + tx;
    if (p < HW) {
      size_t o = ((size_t)b * kS + (s0 + p)) * (size_t)kD + d;
      float x = ts[tx][pp];
      float pv = tp[tx][pp] + lemb[lvl * kD + d];
      posbf[o] = f2bf(pv);
      xbf[o] = f2bf(x);
      qbf[o] = f2bf(x + pv);
    }
  }
}

// ---------------------------------------------------------------------------
// Weight convert+transpose: W fp32 [NL][K][N] -> Wt bf16 [NL][rows][K] at rowoff
// ---------------------------------------------------------------------------
__global__ __launch_bounds__(256) void wconv_k(
    const float* __restrict__ W, unsigned short* __restrict__ Wt,
    int K, int N, int rowoff, int rowstotal)
{
  __shared__ float t[32][33];
  const int l = blockIdx.z;
  const int n0 = blockIdx.x * 32, k0 = blockIdx.y * 32;
  const int tx = threadIdx.x & 31, ty = threadIdx.x >> 5;
  const float* Wl = W + (size_t)l * K * N;
  unsigned short* Wtl = Wt + (size_t)l * rowstotal * K;
  for (int kk = ty; kk < 32; kk += 8)
    t[kk][tx] = Wl[(size_t)(k0 + kk) * N + n0 + tx];
  __syncthreads();
  for (int nn = ty; nn < 32; nn += 8)
    Wtl[(size_t)(rowoff + n0 + nn) * K + k0 + tx] = f2bf(t[tx][nn]);
}

__global__ __launch_bounds__(256) void biaspack_k(
    const float* __restrict__ ob, const float* __restrict__ ab,
    float* __restrict__ qb)
{
  int i = blockIdx.x * 256 + threadIdx.x;
  if (i >= kNL * 384) return;
  int l = i / 384, c = i - l * 384;
  qb[i] = (c < 256) ? ob[l * 256 + c] : ab[l * 128 + (c - 256)];
}

// ---------------------------------------------------------------------------
// Reference-point table: ref[s] = (rx, ry) in [0,1], once per call.
// ---------------------------------------------------------------------------
__global__ __launch_bounds__(256) void refxy_k(float* __restrict__ ref)
{
  int s = blockIdx.x * 256 + threadIdx.x;
  if (s >= kS) return;
  int ls, side;
  if (s < 12544)      { ls = s;         side = 112; }
  else if (s < 15680) { ls = s - 12544; side = 56;  }
  else if (s < 16464) { ls = s - 15680; side = 28;  }
  else                { ls = s - 16464; side = 14;  }
  const float inv = 1.0f / (float)side;
  ref[s * 2 + 0] = ((ls % side) + 0.5f) * inv;
  ref[s * 2 + 1] = ((ls / side) + 0.5f) * inv;
}

// ---------------------------------------------------------------------------
// bf16 MFMA GEMM, BM=64/BN=128: 256 threads, 4 waves 2x2 of 32x64,
// depth-2 counted-vmcnt pipeline. Used for ff1.
// ---------------------------------------------------------------------------
template<int RELU, int OUTBF>
__global__ __launch_bounds__(256) void hgemm64_k(
    const unsigned short* __restrict__ A, const unsigned short* __restrict__ Bt,
    const float* __restrict__ bias, void* __restrict__ Cout, int N, int K)
{
  __shared__ unsigned short As[2][64 * 32];    // 2x4 KB
  __shared__ unsigned short Bs[2][128 * 32];   // 2x8 KB
  const int tid = threadIdx.x;
  const int bm = blockIdx.y * 64;
  const int bn = blockIdx.x * 128;
  const int lane = tid & 63;
  const int wave = tid >> 6;
  const int wr = (wave >> 1) * 32, wc = (wave & 1) * 64;
  const int l15 = lane & 15, l4 = lane >> 4;

  f32x4 acc[2][4] = {};

  const unsigned short* A0 = A + (size_t)(bm + (tid >> 2)) * K + ((tid & 3) << 3);
  const int cb1 = 256 + tid;
  const unsigned short* B0 = Bt + (size_t)(bn + (tid >> 2)) * K + ((tid & 3) << 3);
  const unsigned short* B1 = Bt + (size_t)(bn + (cb1 >> 2)) * K + ((cb1 & 3) << 3);

#define STAGE64(buf, k0)                                                       \
  do {                                                                         \
    GLOAD_LDS16(A0 + (k0), (char*)As[buf] + tid * 16);                         \
    GLOAD_LDS16(B0 + (k0), (char*)Bs[buf] + tid * 16);                         \
    GLOAD_LDS16(B1 + (k0), (char*)Bs[buf] + cb1 * 16);                         \
  } while (0)

  const int nt = K >> 5;
  STAGE64(0, 0);
  STAGE64(1, 32);
  for (int k = 0; k < nt; ++k) {
    if (k + 1 < nt) asm volatile("s_waitcnt vmcnt(3)" ::: "memory");
    else            asm volatile("s_waitcnt vmcnt(0)" ::: "memory");
    SBARRIER();
    __builtin_amdgcn_sched_barrier(0);
    const int cur = k & 1;
    bf16x8 af[2], bfr[4];
#pragma unroll
    for (int m = 0; m < 2; ++m)
      af[m] = *(const bf16x8*)&As[cur][(wr + m * 16 + l15) * 32 + l4 * 8];
#pragma unroll
    for (int n = 0; n < 4; ++n)
      bfr[n] = *(const bf16x8*)&Bs[cur][(wc + n * 16 + l15) * 32 + l4 * 8];
#pragma unroll
    for (int m = 0; m < 2; ++m)
#pragma unroll
      for (int n = 0; n < 4; ++n)
        acc[m][n] = __builtin_amdgcn_mfma_f32_16x16x32_bf16(
            af[m], bfr[n], acc[m][n], 0, 0, 0);
    SBARRIER();
    if (k + 2 < nt) STAGE64(cur, (k + 2) * 32);
  }
#undef STAGE64

#pragma unroll
  for (int n = 0; n < 4; ++n) {
    const int col = bn + wc + n * 16 + l15;
    const float bv = bias[col];
#pragma unroll
    for (int m = 0; m < 2; ++m) {
#pragma unroll
      for (int j = 0; j < 4; ++j) {
        const int row = bm + wr + m * 16 + l4 * 4 + j;
        float v = acc[m][n][j] + bv;
        if (RELU) v = fmaxf(v, 0.f);
        if (OUTBF)
          ((unsigned short*)Cout)[(size_t)row * N + col] = f2bf(v);
        else
          ((float*)Cout)[(size_t)row * N + col] = v;
      }
    }
  }
}

// ---------------------------------------------------------------------------
// Merged qout+val GEMM: grid (5, kMT64). bx<3: qout = (x+pos)@qw + qbias
// (N=384, fp16 out); bx>=3: val = x@vw + vbias (N=256, bf16 out). K=256.
// ---------------------------------------------------------------------------
__global__ __launch_bounds__(256) void qvgemm_k(
    const unsigned short* __restrict__ Aq, const unsigned short* __restrict__ Ax,
    const unsigned short* __restrict__ Bq, const unsigned short* __restrict__ Bv,
    const float* __restrict__ biasq, const float* __restrict__ biasv,
    _Float16* __restrict__ Cq, unsigned short* __restrict__ Cv)
{
  constexpr int K = 256;
  __shared__ unsigned short As[2][64 * 32];
  __shared__ unsigned short Bs[2][128 * 32];
  const int tid = threadIdx.x;
  const int bx = blockIdx.x;           // 0..4
  const bool isv = bx >= 3;
  const int bn = (isv ? bx - 3 : bx) * 128;
  const int bm = blockIdx.y * 64;
  const unsigned short* A  = isv ? Ax : Aq;
  const unsigned short* Bt = isv ? Bv : Bq;
  const float* bias = isv ? biasv : biasq;
  const int lane = tid & 63;
  const int wave = tid >> 6;
  const int wr = (wave >> 1) * 32, wc = (wave & 1) * 64;
  const int l15 = lane & 15, l4 = lane >> 4;

  f32x4 acc[2][4] = {};

  const unsigned short* A0 = A + (size_t)(bm + (tid >> 2)) * K + ((tid & 3) << 3);
  const int cb1 = 256 + tid;
  const unsigned short* B0 = Bt + (size_t)(bn + (tid >> 2)) * K + ((tid & 3) << 3);
  const unsigned short* B1 = Bt + (size_t)(bn + (cb1 >> 2)) * K + ((cb1 & 3) << 3);

#define STAGEQV(buf, k0)                                                       \
  do {                                                                         \
    GLOAD_LDS16(A0 + (k0), (char*)As[buf] + tid * 16);                         \
    GLOAD_LDS16(B0 + (k0), (char*)Bs[buf] + tid * 16);                         \
    GLOAD_LDS16(B1 + (k0), (char*)Bs[buf] + cb1 * 16);                         \
  } while (0)

  const int nt = K >> 5;               // 8
  STAGEQV(0, 0);
  STAGEQV(1, 32);
  for (int k = 0; k < nt; ++k) {
    if (k + 1 < nt) asm volatile("s_waitcnt vmcnt(3)" ::: "memory");
    else            asm volatile("s_waitcnt vmcnt(0)" ::: "memory");
    SBARRIER();
    __builtin_amdgcn_sched_barrier(0);
    const int cur = k & 1;
    bf16x8 af[2], bfr[4];
#pragma unroll
    for (int m = 0; m < 2; ++m)
      af[m] = *(const bf16x8*)&As[cur][(wr + m * 16 + l15) * 32 + l4 * 8];
#pragma unroll
    for (int n = 0; n < 4; ++n)
      bfr[n] = *(const bf16x8*)&Bs[cur][(wc + n * 16 + l15) * 32 + l4 * 8];
#pragma unroll
    for (int m = 0; m < 2; ++m)
#pragma unroll
      for (int n = 0; n < 4; ++n)
        acc[m][n] = __builtin_amdgcn_mfma_f32_16x16x32_bf16(
            af[m], bfr[n], acc[m][n], 0, 0, 0);
    SBARRIER();
    if (k + 2 < nt) STAGEQV(cur, (k + 2) * 32);
  }
#undef STAGEQV

#pragma unroll
  for (int n = 0; n < 4; ++n) {
    const int col = bn + wc + n * 16 + l15;
    const float bv = bias[col];
#pragma unroll
    for (int m = 0; m < 2; ++m) {
#pragma unroll
      for (int j = 0; j < 4; ++j) {
        const int row = bm + wr + m * 16 + l4 * 4 + j;
        float v = acc[m][n][j] + bv;
        if (isv)
          Cv[(size_t)row * 256 + col] = f2bf(v);
        else
          Cq[(size_t)row * 384 + col] = (_Float16)v;
      }
    }
  }
}

// ---------------------------------------------------------------------------
// bf16 MFMA GEMM with fused bias+residual(bf16)+LayerNorm epilogue.
// BM=64, BN=256, 512 threads (8 waves 2Mx4N of 32x64), BK=32, depth-2
// counted-vmcnt pipeline (r12 structure). x-state is bf16 only.
// OUTDST=0: write xbf (+qbf if WQ). OUTDST=1: write yout fp32 (d_out).
// ---------------------------------------------------------------------------
template<int WQ, int OUTDST>
__global__ __launch_bounds__(512) void hgemmln_k(
    const unsigned short* __restrict__ A, const unsigned short* __restrict__ Bt,
    const float* __restrict__ bias, const unsigned short* __restrict__ Rsd,
    const float* __restrict__ g, const float* __restrict__ beta,
    const unsigned short* __restrict__ posbf, float* __restrict__ yout,
    unsigned short* __restrict__ xbf, unsigned short* __restrict__ qbf, int K)
{
  __shared__ unsigned short As[2][64 * 32];    // 2 x 4 KB
  __shared__ unsigned short Bs[2][256 * 32];   // 2 x 16 KB
  __shared__ float ssum[64][5];
  __shared__ float ssq[64][5];
  const int tid = threadIdx.x;
  const int bm = blockIdx.x * 64;
  const int lane = tid & 63;
  const int wave = tid >> 6;          // 0..7
  const int wm = wave >> 2;           // 0..1
  const int wn = wave & 3;            // 0..3
  const int wc = wn * 64;
  const int l15 = lane & 15, l4 = lane >> 4;

  f32x4 acc[2][4] = {};

  const unsigned short* Aq = A + (size_t)(bm + (tid >> 2)) * K + ((tid & 3) << 3);
  const unsigned short* Bq0 = Bt + (size_t)(tid >> 2) * K + ((tid & 3) << 3);
  const unsigned short* Bq1 = Bt + (size_t)(128 + (tid >> 2)) * K + ((tid & 3) << 3);

#define STAGE_LN(buf, k0)                                                      \
  do {                                                                         \
    if (tid < 256) GLOAD_LDS16(Aq + (k0), (char*)As[buf] + tid * 16);          \
    GLOAD_LDS16(Bq0 + (k0), (char*)Bs[buf] + tid * 16);                        \
    GLOAD_LDS16(Bq1 + (k0), (char*)Bs[buf] + (512 + tid) * 16);                \
  } while (0)

  const int nt = K >> 5;
  STAGE_LN(0, 0);
  STAGE_LN(1, 32);
  for (int k = 0; k < nt; ++k) {
    if (k + 1 < nt) {
      if (wave < 4) asm volatile("s_waitcnt vmcnt(3)" ::: "memory");
      else          asm volatile("s_waitcnt vmcnt(2)" ::: "memory");
    } else {
      asm volatile("s_waitcnt vmcnt(0)" ::: "memory");
    }
    SBARRIER();
    __builtin_amdgcn_sched_barrier(0);
    const int cur = k & 1;
    bf16x8 af[2], bfr[4];
#pragma unroll
    for (int m = 0; m < 2; ++m)
      af[m] = *(const bf16x8*)&As[cur][(wm * 32 + m * 16 + l15) * 32 + l4 * 8];
#pragma unroll
    for (int n = 0; n < 4; ++n)
      bfr[n] = *(const bf16x8*)&Bs[cur][(wc + n * 16 + l15) * 32 + l4 * 8];
#pragma unroll
    for (int m = 0; m < 2; ++m)
#pragma unroll
      for (int n = 0; n < 4; ++n)
        acc[m][n] = __builtin_amdgcn_mfma_f32_16x16x32_bf16(
            af[m], bfr[n], acc[m][n], 0, 0, 0);
    SBARRIER();
    if (k + 2 < nt) STAGE_LN(cur, (k + 2) * 32);
  }
#undef STAGE_LN

  float bv[4], gv[4], btv[4];
#pragma unroll
  for (int n = 0; n < 4; ++n) {
    const int col = wc + n * 16 + l15;
    bv[n] = bias[col];
    gv[n] = g[col];
    btv[n] = beta[col];
  }
#pragma unroll
  for (int m = 0; m < 2; ++m) {
#pragma unroll
    for (int j = 0; j < 4; ++j) {
      const int row = bm + wm * 32 + m * 16 + l4 * 4 + j;
#pragma unroll
      for (int n = 0; n < 4; ++n)
        acc[m][n][j] += bv[n] + bf2f(Rsd[(size_t)row * kD + wc + n * 16 + l15]);
    }
  }
#pragma unroll
  for (int m = 0; m < 2; ++m) {
#pragma unroll
    for (int j = 0; j < 4; ++j) {
      float s = acc[m][0][j] + acc[m][1][j] + acc[m][2][j] + acc[m][3][j];
      float q = acc[m][0][j] * acc[m][0][j] + acc[m][1][j] * acc[m][1][j] +
                acc[m][2][j] * acc[m][2][j] + acc[m][3][j] * acc[m][3][j];
#pragma unroll
      for (int d2 = 1; d2 < 16; d2 <<= 1) {
        s += __shfl_xor(s, d2, 64);
        q += __shfl_xor(q, d2, 64);
      }
      if (l15 == 0) {
        const int r = wm * 32 + m * 16 + l4 * 4 + j;
        ssum[r][wn] = s;
        ssq[r][wn] = q;
      }
    }
  }
  __syncthreads();
#pragma unroll
  for (int m = 0; m < 2; ++m) {
#pragma unroll
    for (int j = 0; j < 4; ++j) {
      const int r = wm * 32 + m * 16 + l4 * 4 + j;
      const int row = bm + r;
      const float mean = (ssum[r][0] + ssum[r][1] + ssum[r][2] + ssum[r][3]) *
                         (1.0f / kD);
      const float var = (ssq[r][0] + ssq[r][1] + ssq[r][2] + ssq[r][3]) *
                        (1.0f / kD) - mean * mean;
      const float rstd = rsqrtf(var + 1e-5f);
      if (row < kM) {
#pragma unroll
        for (int n = 0; n < 4; ++n) {
          const int col = wc + n * 16 + l15;
          const float y = (acc[m][n][j] - mean) * rstd * gv[n] + btv[n];
          const size_t o = (size_t)row * kD + col;
          if (OUTDST) {
            yout[o] = y;
          } else {
            xbf[o] = f2bf(y);
            if (WQ) qbf[o] = f2bf(y + bf2f(posbf[o]));
          }
        }
      }
    }
  }
}

// ---------------------------------------------------------------------------
// MS deformable attention sampling (+fused softmax), 8 queries per block,
// XCD-bijective block swizzle.
// ---------------------------------------------------------------------------
__global__ __launch_bounds__(256) void msdeform_k(
    const unsigned short* __restrict__ val, const _Float16* __restrict__ qout,
    const float* __restrict__ ref, unsigned short* __restrict__ outbf)
{
  __shared__ int   sIdx[4][8][128];   // [corner][q][sp*8+h] byte offsets
  __shared__ float sW[4][8][128];
  // bijective XCD swizzle (m204): nwg = kM/8 = 4165, q8 = 520, r8 = 5
  const int bid = blockIdx.x;
  const int xcd = bid & 7;
  const int jj  = bid >> 3;
  const int wg  = (xcd < 5 ? xcd * 521 : 5 * 521 + (xcd - 5) * 520) + jj;
  const int bs0 = wg * 8;
  const int tid = threadIdx.x;

#pragma unroll
  for (int it = 0; it < 4; ++it) {
    const int item = tid + it * 256;
    const int q = item >> 7;         // 0..7
    const int t = item & 127;        // h*16 + l*4 + p
    const int bs = bs0 + q;
    const int b = bs / kS, s = bs - b * kS;
    const int l = (t & 15) >> 2;

    const float logit = (float)qout[(size_t)bs * 384 + 256 + t];
    float mx = logit;
#pragma unroll
    for (int d2 = 1; d2 < 16; d2 <<= 1) mx = fmaxf(mx, __shfl_xor(mx, d2, 64));
    float e = __expf(logit - mx);
    float sm = e;
#pragma unroll
    for (int d2 = 1; d2 < 16; d2 <<= 1) sm += __shfl_xor(sm, d2, 64);
    const float a = e / sm;

    const float rfx = ref[s * 2 + 0];
    const float rfy = ref[s * 2 + 1];
    const int side  = 112 >> l;
    const int start = (l >= 1 ? 12544 : 0) + (l >= 2 ? 3136 : 0) + (l >= 3 ? 784 : 0);
    const float ox = (float)qout[(size_t)bs * 384 + t * 2 + 0];
    const float oy = (float)qout[(size_t)bs * 384 + t * 2 + 1];
    const float xx = fmaf(rfx, (float)side, ox) - 0.5f;
    const float yy = fmaf(rfy, (float)side, oy) - 0.5f;
    const float xf = floorf(xx), yf = floorf(yy);
    const float lx = xx - xf, ly = yy - yf;
    const int x0 = (int)xf, y0 = (int)yf;
    const float w00 = (1.f - lx) * (1.f - ly) * a, w10 = lx * (1.f - ly) * a;
    const float w01 = (1.f - lx) * ly * a,         w11 = lx * ly * a;
    const bool xv0 = (unsigned)x0 < (unsigned)side, xv1 = (unsigned)(x0 + 1) < (unsigned)side;
    const bool yv0 = (unsigned)y0 < (unsigned)side, yv1 = (unsigned)(y0 + 1) < (unsigned)side;
    const int cx0 = min(max(x0, 0), side - 1), cx1 = min(max(x0 + 1, 0), side - 1);
    const int cy0 = min(max(y0, 0), side - 1), cy1 = min(max(y0 + 1, 0), side - 1);
    const int rowbase = b * kS + start;
    const int t2 = (t & 15) * 8 + (t >> 4);   // sp*8 + h
    sIdx[0][q][t2] = (rowbase + cy0 * side + cx0) << 9;   // *512 B/row (bf16)
    sIdx[1][q][t2] = (rowbase + cy0 * side + cx1) << 9;
    sIdx[2][q][t2] = (rowbase + cy1 * side + cx0) << 9;
    sIdx[3][q][t2] = (rowbase + cy1 * side + cx1) << 9;
    sW[0][q][t2] = (xv0 && yv0) ? w00 : 0.f;
    sW[1][q][t2] = (xv1 && yv0) ? w10 : 0.f;
    sW[2][q][t2] = (xv0 && yv1) ? w01 : 0.f;
    sW[3][q][t2] = (xv1 && yv1) ? w11 : 0.f;
  }
  __syncthreads();

  const int q  = tid >> 5;            // 0..7 (2 queries per wave)
  const int h  = (tid >> 2) & 7;      // 0..7
  const int l4 = tid & 3;             // 0..3 (16B = 8 bf16 sub-row)
  const char* vbase = (const char*)val + h * 64 + l4 * 16;

  float a0 = 0.f, a1 = 0.f, a2 = 0.f, a3 = 0.f;
  float a4 = 0.f, a5 = 0.f, a6 = 0.f, a7 = 0.f;
#pragma unroll
  for (int sp = 0; sp < 16; ++sp) {
    const int t2 = sp * 8 + h;
#pragma unroll
    for (int c = 0; c < 4; ++c) {
      const int off = sIdx[c][q][t2];
      const float w = sW[c][q][t2];
      const uint4 v = *(const uint4*)(vbase + off);
      a0 = fmaf(w, bflo(v.x), a0); a1 = fmaf(w, bfhi(v.x), a1);
      a2 = fmaf(w, bflo(v.y), a2); a3 = fmaf(w, bfhi(v.y), a3);
      a4 = fmaf(w, bflo(v.z), a4); a5 = fmaf(w, bfhi(v.z), a5);
      a6 = fmaf(w, bflo(v.w), a6); a7 = fmaf(w, bfhi(v.w), a7);
    }
  }
  bf16x8 o;
  o[0] = (short)f2bf(a0); o[1] = (short)f2bf(a1);
  o[2] = (short)f2bf(a2); o[3] = (short)f2bf(a3);
  o[4] = (short)f2bf(a4); o[5] = (short)f2bf(a5);
  o[6] = (short)f2bf(a6); o[7] = (short)f2bf(a7);
  *(bf16x8*)(outbf + (size_t)(bs0 + q) * 256 + h * 32 + l4 * 8) = o;
}

// ---------------------------------------------------------------------------
__global__ void tail_k(float* __restrict__ out)
{
  if (threadIdx.x == 0) {
    const size_t n = (size_t)kM * kD;
    out[n + 0] = 112.f; out[n + 1] = 112.f;
    out[n + 2] = 56.f;  out[n + 3] = 56.f;
    out[n + 4] = 28.f;  out[n + 5] = 28.f;
    out[n + 6] = 14.f;  out[n + 7] = 14.f;
    out[n + 8] = 0.f;   out[n + 9] = 12544.f;
    out[n + 10] = 15680.f; out[n + 11] = 16464.f;
  }
}

// ---------------------------------------------------------------------------
extern "C" void kernel_launch(void* const* d_in, const int* in_sizes, int n_in,
                              void* d_out, int out_size, void* d_ws, size_t ws_size,
                              hipStream_t stream)
{
  const float* src[4] = {(const float*)d_in[0], (const float*)d_in[2],
                         (const float*)d_in[4], (const float*)d_in[6]};
  const float* pos[4] = {(const float*)d_in[1], (const float*)d_in[3],
                         (const float*)d_in[5], (const float*)d_in[7]};
  const float* lemb  = (const float*)d_in[8];
  const float* off_w = (const float*)d_in[9];
  const float* off_b = (const float*)d_in[10];
  const float* aw_w  = (const float*)d_in[11];
  const float* aw_b  = (const float*)d_in[12];
  const float* val_w = (const float*)d_in[13];
  const float* val_b = (const float*)d_in[14];
  const float* out_w = (const float*)d_in[15];
  const float* out_b = (const float*)d_in[16];
  const float* ln1_s = (const float*)d_in[17];
  const float* ln1_b = (const float*)d_in[18];
  const float* ff1_w = (const float*)d_in[19];
  const float* ff1_b = (const float*)d_in[20];
  const float* ff2_w = (const float*)d_in[21];
  const float* ff2_b = (const float*)d_in[22];
  const float* ln2_s = (const float*)d_in[23];
  const float* ln2_b = (const float*)d_in[24];

  const size_t SZ = (size_t)kMp * kD;      // 8,552,448 floats
  float* ws   = (float*)d_ws;
  _Float16* qoutH = (_Float16*)(ws + SZ);             // [Mp][384] = 0.75 SZ
  unsigned short* valbf = (unsigned short*)(ws + SZ + (3 * SZ) / 4); // 0.5 SZ
  unsigned short* attbf = valbf + SZ;                 // 0.5 SZ
  unsigned short* ffbf  = (unsigned short*)(ws + SZ); // [Mp][1024], aliases ^
  unsigned short* posbf = (unsigned short*)(ws + 3 * SZ);      // 0.5 SZ
  unsigned short* qbf   = posbf + SZ;                          // 0.5 SZ
  unsigned short* xbf   = qbf + SZ;                            // 0.5 SZ
  unsigned short* wts   = (unsigned short*)(ws + 4 * SZ + SZ / 2);
  unsigned short* qwT  = wts;                    // [NL][384][256]
  unsigned short* valT = qwT + kNL * 384 * 256;  // [NL][256][256]
  unsigned short* outT = valT + kNL * 256 * 256;
  unsigned short* ff1T = outT + kNL * 256 * 256; // [NL][1024][256]
  unsigned short* ff2T = ff1T + kNL * 1024 * 256;// [NL][256][1024]
  float* qbias = (float*)(ff2T + kNL * 256 * 1024); // [NL][384]
  float* reftab = qbias + kNL * 384;                // [kS][2]

  // --- weight prep + ref table ---
  wconv_k<<<dim3(256 / 32, 256 / 32, kNL), 256, 0, stream>>>(off_w, qwT, 256, 256, 0, 384);
  wconv_k<<<dim3(128 / 32, 256 / 32, kNL), 256, 0, stream>>>(aw_w,  qwT, 256, 128, 256, 384);
  wconv_k<<<dim3(256 / 32, 256 / 32, kNL), 256, 0, stream>>>(val_w, valT, 256, 256, 0, 256);
  wconv_k<<<dim3(256 / 32, 256 / 32, kNL), 256, 0, stream>>>(out_w, outT, 256, 256, 0, 256);
  wconv_k<<<dim3(1024 / 32, 256 / 32, kNL), 256, 0, stream>>>(ff1_w, ff1T, 256, 1024, 0, 1024);
  wconv_k<<<dim3(256 / 32, 1024 / 32, kNL), 256, 0, stream>>>(ff2_w, ff2T, 1024, 256, 0, 256);
  biaspack_k<<<(kNL * 384 + 255) / 256, 256, 0, stream>>>(off_b, aw_b, qbias);
  refxy_k<<<(kS + 255) / 256, 256, 0, stream>>>(reftab);

  // --- build bf16 x, q, pos ---
  const int sides[4]  = {112, 56, 28, 14};
  const int starts[4] = {0, 12544, 15680, 16464};
  for (int l = 0; l < 4; ++l) {
    int HW = sides[l] * sides[l];
    dim3 g((HW + 31) / 32, kD / 32, kB);
    build_xpos_k<<<g, dim3(32, 8), 0, stream>>>(src[l], pos[l], lemb, posbf,
                                                xbf, qbf, HW, starts[l], l);
  }

  const dim3 blk(256);
  for (int i = 0; i < kNL; ++i) {
    // qout = (x+pos) @ [off_w|aw_w] + qbias (fp16)  AND  val = x @ val_w + b
    qvgemm_k<<<dim3(5, kMT64), blk, 0, stream>>>(
        qbf, xbf, qwT + (size_t)i * 384 * 256, valT + (size_t)i * 256 * 256,
        qbias + i * 384, val_b + i * 256, qoutH, valbf);
    // sampling (+softmax fused)
    msdeform_k<<<kM / 8, blk, 0, stream>>>(valbf, qoutH, reftab, attbf);
    // x = LN1(x + attn @ out_w + out_b)  [fused; x-state bf16, in-place]
    hgemmln_k<0, 0><<<kMT64, 512, 0, stream>>>(
        attbf, outT + (size_t)i * 256 * 256, out_b + i * 256, xbf,
        ln1_s + i * kD, ln1_b + i * kD, nullptr, nullptr, xbf, nullptr, 256);
    // ffmid = relu(x @ ff1_w + ff1_b) -> bf16
    hgemm64_k<1, 1><<<dim3(8, kMT64), blk, 0, stream>>>(
        xbf, ff1T + (size_t)i * 1024 * 256, ff1_b + i * 1024, ffbf, 1024, 256);
    // x = LN2(x + ffmid @ ff2_w + ff2_b)  [fused; last layer -> d_out fp32]
    if (i < kNL - 1) {
      hgemmln_k<1, 0><<<kMT64, 512, 0, stream>>>(
          ffbf, ff2T + (size_t)i * 256 * 1024, ff2_b + i * 256, xbf,
          ln2_s + i * kD, ln2_b + i * kD, posbf, nullptr, xbf, qbf, 1024);
    } else {
      hgemmln_k<0, 1><<<kMT64, 512, 0, stream>>>(
          ffbf, ff2T + (size_t)i * 256 * 1024, ff2_b + i * 256, xbf,
          ln2_s + i * kD, ln2_b + i * kD, nullptr, (float*)d_out, nullptr,
          nullptr, 1024);
    }
  }

  tail_k<<<1, 64, 0, stream>>>((float*)d_out);
}

// Round 16
// 1284.166 us; speedup vs baseline: 1.1575x; 1.0084x over previous
//
#include <hip/hip_runtime.h>

// MSDeformAttn Transformer encoder (Deformable-DETR), MI355X.
// Round 16: persistent-tile hgemmln (grid=512, 2 blocks/CU co-resident,
//           tile-loop over 522 row-tiles) to kill the 3T tail quantization.
//           Rest identical to r15.

constexpr int kB  = 2;
constexpr int kD  = 256;
constexpr int kNH = 8;
constexpr int kLV = 4;
constexpr int kNP = 4;
constexpr int kNL = 6;
constexpr int kDFF = 1024;
constexpr int kS  = 16660;                 // 112^2+56^2+28^2+14^2
constexpr int kM  = kB * kS;               // 33320
constexpr int kMp = 33408;                 // 261*128 (padded rows)
constexpr int kMT64 = kMp / 64;            // 522
constexpr int kPERS = 512;                 // persistent grid (2 blocks/CU)

typedef short bf16x8 __attribute__((ext_vector_type(8)));
typedef float f32x4  __attribute__((ext_vector_type(4)));

__device__ __forceinline__ unsigned short f2bf(float x) {
  union { float f; unsigned int u; } v; v.f = x;
  unsigned int r = v.u + 0x7FFFu + ((v.u >> 16) & 1u);
  return (unsigned short)(r >> 16);
}
__device__ __forceinline__ float bf2f(unsigned short u) {
  union { unsigned int u; float f; } v; v.u = ((unsigned int)u) << 16;
  return v.f;
}
__device__ __forceinline__ float bflo(unsigned int u) {
  union { unsigned int u; float f; } v; v.u = u << 16;
  return v.f;
}
__device__ __forceinline__ float bfhi(unsigned int u) {
  union { unsigned int u; float f; } v; v.u = u & 0xFFFF0000u;
  return v.f;
}

#define GLOAD_LDS16(gp, lp)                                                    \
  __builtin_amdgcn_global_load_lds(                                            \
      (const __attribute__((address_space(1))) void*)(gp),                     \
      (__attribute__((address_space(3))) void*)(lp), 16, 0, 0)

#define SBARRIER() asm volatile("s_barrier" ::: "memory")

// ---------------------------------------------------------------------------
// Input flatten+transpose; emits x bf16, q=x+pos bf16, pos bf16.
// ---------------------------------------------------------------------------
__global__ __launch_bounds__(256) void build_xpos_k(
    const float* __restrict__ src, const float* __restrict__ pos,
    const float* __restrict__ lemb, unsigned short* __restrict__ posbf,
    unsigned short* __restrict__ xbf, unsigned short* __restrict__ qbf,
    int HW, int s0, int lvl)
{
  __shared__ float ts[32][33];
  __shared__ float tp[32][33];
  const int b  = blockIdx.z;
  const int p0 = blockIdx.x * 32, d0 = blockIdx.y * 32;
  const int tx = threadIdx.x, ty = threadIdx.y;   // (32, 8)
  for (int dd = ty; dd < 32; dd += 8) {
    int p = p0 + tx;
    if (p < HW) {
      size_t idx = ((size_t)b * kD + (d0 + dd)) * (size_t)HW + p;
      ts[dd][tx] = src[idx];
      tp[dd][tx] = pos[idx];
    }
  }
  __syncthreads();
  for (int pp = ty; pp < 32; pp += 8) {
    int p = p0 + pp, d = d0 + tx;
    if (p < HW) {
      size_t o = ((size_t)b * kS + (s0 + p)) * (size_t)kD + d;
      float x = ts[tx][pp];
      float pv = tp[tx][pp] + lemb[lvl * kD + d];
      posbf[o] = f2bf(pv);
      xbf[o] = f2bf(x);
      qbf[o] = f2bf(x + pv);
    }
  }
}

// ---------------------------------------------------------------------------
// Weight convert+transpose: W fp32 [NL][K][N] -> Wt bf16 [NL][rows][K] at rowoff
// ---------------------------------------------------------------------------
__global__ __launch_bounds__(256) void wconv_k(
    const float* __restrict__ W, unsigned short* __restrict__ Wt,
    int K, int N, int rowoff, int rowstotal)
{
  __shared__ float t[32][33];
  const int l = blockIdx.z;
  const int n0 = blockIdx.x * 32, k0 = blockIdx.y * 32;
  const int tx = threadIdx.x & 31, ty = threadIdx.x >> 5;
  const float* Wl = W + (size_t)l * K * N;
  unsigned short* Wtl = Wt + (size_t)l * rowstotal * K;
  for (int kk = ty; kk < 32; kk += 8)
    t[kk][tx] = Wl[(size_t)(k0 + kk) * N + n0 + tx];
  __syncthreads();
  for (int nn = ty; nn < 32; nn += 8)
    Wtl[(size_t)(rowoff + n0 + nn) * K + k0 + tx] = f2bf(t[tx][nn]);
}

__global__ __launch_bounds__(256) void biaspack_k(
    const float* __restrict__ ob, const float* __restrict__ ab,
    float* __restrict__ qb)
{
  int i = blockIdx.x * 256 + threadIdx.x;
  if (i >= kNL * 384) return;
  int l = i / 384, c = i - l * 384;
  qb[i] = (c < 256) ? ob[l * 256 + c] : ab[l * 128 + (c - 256)];
}

// ---------------------------------------------------------------------------
// Reference-point table: ref[s] = (rx, ry) in [0,1], once per call.
// ---------------------------------------------------------------------------
__global__ __launch_bounds__(256) void refxy_k(float* __restrict__ ref)
{
  int s = blockIdx.x * 256 + threadIdx.x;
  if (s >= kS) return;
  int ls, side;
  if (s < 12544)      { ls = s;         side = 112; }
  else if (s < 15680) { ls = s - 12544; side = 56;  }
  else if (s < 16464) { ls = s - 15680; side = 28;  }
  else                { ls = s - 16464; side = 14;  }
  const float inv = 1.0f / (float)side;
  ref[s * 2 + 0] = ((ls % side) + 0.5f) * inv;
  ref[s * 2 + 1] = ((ls / side) + 0.5f) * inv;
}

// ---------------------------------------------------------------------------
// bf16 MFMA GEMM, BM=64/BN=128: 256 threads, 4 waves 2x2 of 32x64,
// depth-2 counted-vmcnt pipeline. Used for ff1.
// ---------------------------------------------------------------------------
template<int RELU, int OUTBF>
__global__ __launch_bounds__(256) void hgemm64_k(
    const unsigned short* __restrict__ A, const unsigned short* __restrict__ Bt,
    const float* __restrict__ bias, void* __restrict__ Cout, int N, int K)
{
  __shared__ unsigned short As[2][64 * 32];    // 2x4 KB
  __shared__ unsigned short Bs[2][128 * 32];   // 2x8 KB
  const int tid = threadIdx.x;
  const int bm = blockIdx.y * 64;
  const int bn = blockIdx.x * 128;
  const int lane = tid & 63;
  const int wave = tid >> 6;
  const int wr = (wave >> 1) * 32, wc = (wave & 1) * 64;
  const int l15 = lane & 15, l4 = lane >> 4;

  f32x4 acc[2][4] = {};

  const unsigned short* A0 = A + (size_t)(bm + (tid >> 2)) * K + ((tid & 3) << 3);
  const int cb1 = 256 + tid;
  const unsigned short* B0 = Bt + (size_t)(bn + (tid >> 2)) * K + ((tid & 3) << 3);
  const unsigned short* B1 = Bt + (size_t)(bn + (cb1 >> 2)) * K + ((cb1 & 3) << 3);

#define STAGE64(buf, k0)                                                       \
  do {                                                                         \
    GLOAD_LDS16(A0 + (k0), (char*)As[buf] + tid * 16);                         \
    GLOAD_LDS16(B0 + (k0), (char*)Bs[buf] + tid * 16);                         \
    GLOAD_LDS16(B1 + (k0), (char*)Bs[buf] + cb1 * 16);                         \
  } while (0)

  const int nt = K >> 5;
  STAGE64(0, 0);
  STAGE64(1, 32);
  for (int k = 0; k < nt; ++k) {
    if (k + 1 < nt) asm volatile("s_waitcnt vmcnt(3)" ::: "memory");
    else            asm volatile("s_waitcnt vmcnt(0)" ::: "memory");
    SBARRIER();
    __builtin_amdgcn_sched_barrier(0);
    const int cur = k & 1;
    bf16x8 af[2], bfr[4];
#pragma unroll
    for (int m = 0; m < 2; ++m)
      af[m] = *(const bf16x8*)&As[cur][(wr + m * 16 + l15) * 32 + l4 * 8];
#pragma unroll
    for (int n = 0; n < 4; ++n)
      bfr[n] = *(const bf16x8*)&Bs[cur][(wc + n * 16 + l15) * 32 + l4 * 8];
#pragma unroll
    for (int m = 0; m < 2; ++m)
#pragma unroll
      for (int n = 0; n < 4; ++n)
        acc[m][n] = __builtin_amdgcn_mfma_f32_16x16x32_bf16(
            af[m], bfr[n], acc[m][n], 0, 0, 0);
    SBARRIER();
    if (k + 2 < nt) STAGE64(cur, (k + 2) * 32);
  }
#undef STAGE64

#pragma unroll
  for (int n = 0; n < 4; ++n) {
    const int col = bn + wc + n * 16 + l15;
    const float bv = bias[col];
#pragma unroll
    for (int m = 0; m < 2; ++m) {
#pragma unroll
      for (int j = 0; j < 4; ++j) {
        const int row = bm + wr + m * 16 + l4 * 4 + j;
        float v = acc[m][n][j] + bv;
        if (RELU) v = fmaxf(v, 0.f);
        if (OUTBF)
          ((unsigned short*)Cout)[(size_t)row * N + col] = f2bf(v);
        else
          ((float*)Cout)[(size_t)row * N + col] = v;
      }
    }
  }
}

// ---------------------------------------------------------------------------
// Merged qout+val GEMM: grid (5, kMT64). bx<3: qout = (x+pos)@qw + qbias
// (N=384, fp16 out); bx>=3: val = x@vw + vbias (N=256, bf16 out). K=256.
// ---------------------------------------------------------------------------
__global__ __launch_bounds__(256) void qvgemm_k(
    const unsigned short* __restrict__ Aq, const unsigned short* __restrict__ Ax,
    const unsigned short* __restrict__ Bq, const unsigned short* __restrict__ Bv,
    const float* __restrict__ biasq, const float* __restrict__ biasv,
    _Float16* __restrict__ Cq, unsigned short* __restrict__ Cv)
{
  constexpr int K = 256;
  __shared__ unsigned short As[2][64 * 32];
  __shared__ unsigned short Bs[2][128 * 32];
  const int tid = threadIdx.x;
  const int bx = blockIdx.x;           // 0..4
  const bool isv = bx >= 3;
  const int bn = (isv ? bx - 3 : bx) * 128;
  const int bm = blockIdx.y * 64;
  const unsigned short* A  = isv ? Ax : Aq;
  const unsigned short* Bt = isv ? Bv : Bq;
  const float* bias = isv ? biasv : biasq;
  const int lane = tid & 63;
  const int wave = tid >> 6;
  const int wr = (wave >> 1) * 32, wc = (wave & 1) * 64;
  const int l15 = lane & 15, l4 = lane >> 4;

  f32x4 acc[2][4] = {};

  const unsigned short* A0 = A + (size_t)(bm + (tid >> 2)) * K + ((tid & 3) << 3);
  const int cb1 = 256 + tid;
  const unsigned short* B0 = Bt + (size_t)(bn + (tid >> 2)) * K + ((tid & 3) << 3);
  const unsigned short* B1 = Bt + (size_t)(bn + (cb1 >> 2)) * K + ((cb1 & 3) << 3);

#define STAGEQV(buf, k0)                                                       \
  do {                                                                         \
    GLOAD_LDS16(A0 + (k0), (char*)As[buf] + tid * 16);                         \
    GLOAD_LDS16(B0 + (k0), (char*)Bs[buf] + tid * 16);                         \
    GLOAD_LDS16(B1 + (k0), (char*)Bs[buf] + cb1 * 16);                         \
  } while (0)

  const int nt = K >> 5;               // 8
  STAGEQV(0, 0);
  STAGEQV(1, 32);
  for (int k = 0; k < nt; ++k) {
    if (k + 1 < nt) asm volatile("s_waitcnt vmcnt(3)" ::: "memory");
    else            asm volatile("s_waitcnt vmcnt(0)" ::: "memory");
    SBARRIER();
    __builtin_amdgcn_sched_barrier(0);
    const int cur = k & 1;
    bf16x8 af[2], bfr[4];
#pragma unroll
    for (int m = 0; m < 2; ++m)
      af[m] = *(const bf16x8*)&As[cur][(wr + m * 16 + l15) * 32 + l4 * 8];
#pragma unroll
    for (int n = 0; n < 4; ++n)
      bfr[n] = *(const bf16x8*)&Bs[cur][(wc + n * 16 + l15) * 32 + l4 * 8];
#pragma unroll
    for (int m = 0; m < 2; ++m)
#pragma unroll
      for (int n = 0; n < 4; ++n)
        acc[m][n] = __builtin_amdgcn_mfma_f32_16x16x32_bf16(
            af[m], bfr[n], acc[m][n], 0, 0, 0);
    SBARRIER();
    if (k + 2 < nt) STAGEQV(cur, (k + 2) * 32);
  }
#undef STAGEQV

#pragma unroll
  for (int n = 0; n < 4; ++n) {
    const int col = bn + wc + n * 16 + l15;
    const float bv = bias[col];
#pragma unroll
    for (int m = 0; m < 2; ++m) {
#pragma unroll
      for (int j = 0; j < 4; ++j) {
        const int row = bm + wr + m * 16 + l4 * 4 + j;
        float v = acc[m][n][j] + bv;
        if (isv)
          Cv[(size_t)row * 256 + col] = f2bf(v);
        else
          Cq[(size_t)row * 384 + col] = (_Float16)v;
      }
    }
  }
}

// ---------------------------------------------------------------------------
// bf16 MFMA GEMM with fused bias+residual(bf16)+LayerNorm epilogue.
// PERSISTENT: grid kPERS=512, each block loops over tiles bid, bid+512.
// BM=64, BN=256, 512 threads (8 waves 2Mx4N of 32x64), BK=32, depth-2
// counted-vmcnt pipeline. vmcnt(0) drain per tile keeps counts exact.
// ---------------------------------------------------------------------------
template<int WQ, int OUTDST>
__global__ __launch_bounds__(512) void hgemmln_k(
    const unsigned short* __restrict__ A, const unsigned short* __restrict__ Bt,
    const float* __restrict__ bias, const unsigned short* __restrict__ Rsd,
    const float* __restrict__ g, const float* __restrict__ beta,
    const unsigned short* __restrict__ posbf, float* __restrict__ yout,
    unsigned short* __restrict__ xbf, unsigned short* __restrict__ qbf, int K)
{
  __shared__ unsigned short As[2][64 * 32];    // 2 x 4 KB
  __shared__ unsigned short Bs[2][256 * 32];   // 2 x 16 KB
  __shared__ float ssum[64][5];
  __shared__ float ssq[64][5];
  const int tid = threadIdx.x;
  const int lane = tid & 63;
  const int wave = tid >> 6;          // 0..7
  const int wm = wave >> 2;           // 0..1
  const int wn = wave & 3;            // 0..3
  const int wc = wn * 64;
  const int l15 = lane & 15, l4 = lane >> 4;

  const unsigned short* Bq0 = Bt + (size_t)(tid >> 2) * K + ((tid & 3) << 3);
  const unsigned short* Bq1 = Bt + (size_t)(128 + (tid >> 2)) * K + ((tid & 3) << 3);

  float bv[4], gv[4], btv[4];
#pragma unroll
  for (int n = 0; n < 4; ++n) {
    const int col = wc + n * 16 + l15;
    bv[n] = bias[col];
    gv[n] = g[col];
    btv[n] = beta[col];
  }

  for (int tile = blockIdx.x; tile < kMT64; tile += kPERS) {
    const int bm = tile * 64;
    const unsigned short* Aq =
        A + (size_t)(bm + (tid >> 2)) * K + ((tid & 3) << 3);

    f32x4 acc[2][4] = {};

#define STAGE_LN(buf, k0)                                                      \
  do {                                                                         \
    if (tid < 256) GLOAD_LDS16(Aq + (k0), (char*)As[buf] + tid * 16);          \
    GLOAD_LDS16(Bq0 + (k0), (char*)Bs[buf] + tid * 16);                        \
    GLOAD_LDS16(Bq1 + (k0), (char*)Bs[buf] + (512 + tid) * 16);                \
  } while (0)

    const int nt = K >> 5;
    STAGE_LN(0, 0);
    STAGE_LN(1, 32);
    for (int k = 0; k < nt; ++k) {
      if (k + 1 < nt) {
        if (wave < 4) asm volatile("s_waitcnt vmcnt(3)" ::: "memory");
        else          asm volatile("s_waitcnt vmcnt(2)" ::: "memory");
      } else {
        asm volatile("s_waitcnt vmcnt(0)" ::: "memory");
      }
      SBARRIER();
      __builtin_amdgcn_sched_barrier(0);
      const int cur = k & 1;
      bf16x8 af[2], bfr[4];
#pragma unroll
      for (int m = 0; m < 2; ++m)
        af[m] = *(const bf16x8*)&As[cur][(wm * 32 + m * 16 + l15) * 32 + l4 * 8];
#pragma unroll
      for (int n = 0; n < 4; ++n)
        bfr[n] = *(const bf16x8*)&Bs[cur][(wc + n * 16 + l15) * 32 + l4 * 8];
#pragma unroll
      for (int m = 0; m < 2; ++m)
#pragma unroll
        for (int n = 0; n < 4; ++n)
          acc[m][n] = __builtin_amdgcn_mfma_f32_16x16x32_bf16(
              af[m], bfr[n], acc[m][n], 0, 0, 0);
      SBARRIER();
      if (k + 2 < nt) STAGE_LN(cur, (k + 2) * 32);
    }
#undef STAGE_LN

    // epilogue: bias + residual(bf16) + LayerNorm
#pragma unroll
    for (int m = 0; m < 2; ++m) {
#pragma unroll
      for (int j = 0; j < 4; ++j) {
        const int row = bm + wm * 32 + m * 16 + l4 * 4 + j;
#pragma unroll
        for (int n = 0; n < 4; ++n)
          acc[m][n][j] +=
              bv[n] + bf2f(Rsd[(size_t)row * kD + wc + n * 16 + l15]);
      }
    }
#pragma unroll
    for (int m = 0; m < 2; ++m) {
#pragma unroll
      for (int j = 0; j < 4; ++j) {
        float s = acc[m][0][j] + acc[m][1][j] + acc[m][2][j] + acc[m][3][j];
        float q = acc[m][0][j] * acc[m][0][j] + acc[m][1][j] * acc[m][1][j] +
                  acc[m][2][j] * acc[m][2][j] + acc[m][3][j] * acc[m][3][j];
#pragma unroll
        for (int d2 = 1; d2 < 16; d2 <<= 1) {
          s += __shfl_xor(s, d2, 64);
          q += __shfl_xor(q, d2, 64);
        }
        if (l15 == 0) {
          const int r = wm * 32 + m * 16 + l4 * 4 + j;
          ssum[r][wn] = s;
          ssq[r][wn] = q;
        }
      }
    }
    __syncthreads();
#pragma unroll
    for (int m = 0; m < 2; ++m) {
#pragma unroll
      for (int j = 0; j < 4; ++j) {
        const int r = wm * 32 + m * 16 + l4 * 4 + j;
        const int row = bm + r;
        const float mean = (ssum[r][0] + ssum[r][1] + ssum[r][2] + ssum[r][3]) *
                           (1.0f / kD);
        const float var = (ssq[r][0] + ssq[r][1] + ssq[r][2] + ssq[r][3]) *
                          (1.0f / kD) - mean * mean;
        const float rstd = rsqrtf(var + 1e-5f);
        if (row < kM) {
#pragma unroll
          for (int n = 0; n < 4; ++n) {
            const int col = wc + n * 16 + l15;
            const float y = (acc[m][n][j] - mean) * rstd * gv[n] + btv[n];
            const size_t o = (size_t)row * kD + col;
            if (OUTDST) {
              yout[o] = y;
            } else {
              xbf[o] = f2bf(y);
              if (WQ) qbf[o] = f2bf(y + bf2f(posbf[o]));
            }
          }
        }
      }
    }
    // drain stores so next tile's counted vmcnt waits are exact;
    // barrier so no wave begins next tile's staging early.
    asm volatile("s_waitcnt vmcnt(0)" ::: "memory");
    SBARRIER();
  }
}

// ---------------------------------------------------------------------------
// MS deformable attention sampling (+fused softmax), 8 queries per block,
// XCD-bijective block swizzle.
// ---------------------------------------------------------------------------
__global__ __launch_bounds__(256) void msdeform_k(
    const unsigned short* __restrict__ val, const _Float16* __restrict__ qout,
    const float* __restrict__ ref, unsigned short* __restrict__ outbf)
{
  __shared__ int   sIdx[4][8][128];   // [corner][q][sp*8+h] byte offsets
  __shared__ float sW[4][8][128];
  // bijective XCD swizzle (m204): nwg = kM/8 = 4165, q8 = 520, r8 = 5
  const int bid = blockIdx.x;
  const int xcd = bid & 7;
  const int jj  = bid >> 3;
  const int wg  = (xcd < 5 ? xcd * 521 : 5 * 521 + (xcd - 5) * 520) + jj;
  const int bs0 = wg * 8;
  const int tid = threadIdx.x;

#pragma unroll
  for (int it = 0; it < 4; ++it) {
    const int item = tid + it * 256;
    const int q = item >> 7;         // 0..7
    const int t = item & 127;        // h*16 + l*4 + p
    const int bs = bs0 + q;
    const int b = bs / kS, s = bs - b * kS;
    const int l = (t & 15) >> 2;

    const float logit = (float)qout[(size_t)bs * 384 + 256 + t];
    float mx = logit;
#pragma unroll
    for (int d2 = 1; d2 < 16; d2 <<= 1) mx = fmaxf(mx, __shfl_xor(mx, d2, 64));
    float e = __expf(logit - mx);
    float sm = e;
#pragma unroll
    for (int d2 = 1; d2 < 16; d2 <<= 1) sm += __shfl_xor(sm, d2, 64);
    const float a = e / sm;

    const float rfx = ref[s * 2 + 0];
    const float rfy = ref[s * 2 + 1];
    const int side  = 112 >> l;
    const int start = (l >= 1 ? 12544 : 0) + (l >= 2 ? 3136 : 0) + (l >= 3 ? 784 : 0);
    const float ox = (float)qout[(size_t)bs * 384 + t * 2 + 0];
    const float oy = (float)qout[(size_t)bs * 384 + t * 2 + 1];
    const float xx = fmaf(rfx, (float)side, ox) - 0.5f;
    const float yy = fmaf(rfy, (float)side, oy) - 0.5f;
    const float xf = floorf(xx), yf = floorf(yy);
    const float lx = xx - xf, ly = yy - yf;
    const int x0 = (int)xf, y0 = (int)yf;
    const float w00 = (1.f - lx) * (1.f - ly) * a, w10 = lx * (1.f - ly) * a;
    const float w01 = (1.f - lx) * ly * a,         w11 = lx * ly * a;
    const bool xv0 = (unsigned)x0 < (unsigned)side, xv1 = (unsigned)(x0 + 1) < (unsigned)side;
    const bool yv0 = (unsigned)y0 < (unsigned)side, yv1 = (unsigned)(y0 + 1) < (unsigned)side;
    const int cx0 = min(max(x0, 0), side - 1), cx1 = min(max(x0 + 1, 0), side - 1);
    const int cy0 = min(max(y0, 0), side - 1), cy1 = min(max(y0 + 1, 0), side - 1);
    const int rowbase = b * kS + start;
    const int t2 = (t & 15) * 8 + (t >> 4);   // sp*8 + h
    sIdx[0][q][t2] = (rowbase + cy0 * side + cx0) << 9;   // *512 B/row (bf16)
    sIdx[1][q][t2] = (rowbase + cy0 * side + cx1) << 9;
    sIdx[2][q][t2] = (rowbase + cy1 * side + cx0) << 9;
    sIdx[3][q][t2] = (rowbase + cy1 * side + cx1) << 9;
    sW[0][q][t2] = (xv0 && yv0) ? w00 : 0.f;
    sW[1][q][t2] = (xv1 && yv0) ? w10 : 0.f;
    sW[2][q][t2] = (xv0 && yv1) ? w01 : 0.f;
    sW[3][q][t2] = (xv1 && yv1) ? w11 : 0.f;
  }
  __syncthreads();

  const int q  = tid >> 5;            // 0..7 (2 queries per wave)
  const int h  = (tid >> 2) & 7;      // 0..7
  const int l4 = tid & 3;             // 0..3 (16B = 8 bf16 sub-row)
  const char* vbase = (const char*)val + h * 64 + l4 * 16;

  float a0 = 0.f, a1 = 0.f, a2 = 0.f, a3 = 0.f;
  float a4 = 0.f, a5 = 0.f, a6 = 0.f, a7 = 0.f;
#pragma unroll
  for (int sp = 0; sp < 16; ++sp) {
    const int t2 = sp * 8 + h;
#pragma unroll
    for (int c = 0; c < 4; ++c) {
      const int off = sIdx[c][q][t2];
      const float w = sW[c][q][t2];
      const uint4 v = *(const uint4*)(vbase + off);
      a0 = fmaf(w, bflo(v.x), a0); a1 = fmaf(w, bfhi(v.x), a1);
      a2 = fmaf(w, bflo(v.y), a2); a3 = fmaf(w, bfhi(v.y), a3);
      a4 = fmaf(w, bflo(v.z), a4); a5 = fmaf(w, bfhi(v.z), a5);
      a6 = fmaf(w, bflo(v.w), a6); a7 = fmaf(w, bfhi(v.w), a7);
    }
  }
  bf16x8 o;
  o[0] = (short)f2bf(a0); o[1] = (short)f2bf(a1);
  o[2] = (short)f2bf(a2); o[3] = (short)f2bf(a3);
  o[4] = (short)f2bf(a4); o[5] = (short)f2bf(a5);
  o[6] = (short)f2bf(a6); o[7] = (short)f2bf(a7);
  *(bf16x8*)(outbf + (size_t)(bs0 + q) * 256 + h * 32 + l4 * 8) = o;
}

// ---------------------------------------------------------------------------
__global__ void tail_k(float* __restrict__ out)
{
  if (threadIdx.x == 0) {
    const size_t n = (size_t)kM * kD;
    out[n + 0] = 112.f; out[n + 1] = 112.f;
    out[n + 2] = 56.f;  out[n + 3] = 56.f;
    out[n + 4] = 28.f;  out[n + 5] = 28.f;
    out[n + 6] = 14.f;  out[n + 7] = 14.f;
    out[n + 8] = 0.f;   out[n + 9] = 12544.f;
    out[n + 10] = 15680.f; out[n + 11] = 16464.f;
  }
}

// ---------------------------------------------------------------------------
extern "C" void kernel_launch(void* const* d_in, const int* in_sizes, int n_in,
                              void* d_out, int out_size, void* d_ws, size_t ws_size,
                              hipStream_t stream)
{
  const float* src[4] = {(const float*)d_in[0], (const float*)d_in[2],
                         (const float*)d_in[4], (const float*)d_in[6]};
  const float* pos[4] = {(const float*)d_in[1], (const float*)d_in[3],
                         (const float*)d_in[5], (const float*)d_in[7]};
  const float* lemb  = (const float*)d_in[8];
  const float* off_w = (const float*)d_in[9];
  const float* off_b = (const float*)d_in[10];
  const float* aw_w  = (const float*)d_in[11];
  const float* aw_b  = (const float*)d_in[12];
  const float* val_w = (const float*)d_in[13];
  const float* val_b = (const float*)d_in[14];
  const float* out_w = (const float*)d_in[15];
  const float* out_b = (const float*)d_in[16];
  const float* ln1_s = (const float*)d_in[17];
  const float* ln1_b = (const float*)d_in[18];
  const float* ff1_w = (const float*)d_in[19];
  const float* ff1_b = (const float*)d_in[20];
  const float* ff2_w = (const float*)d_in[21];
  const float* ff2_b = (const float*)d_in[22];
  const float* ln2_s = (const float*)d_in[23];
  const float* ln2_b = (const float*)d_in[24];

  const size_t SZ = (size_t)kMp * kD;      // 8,552,448 floats
  float* ws   = (float*)d_ws;
  _Float16* qoutH = (_Float16*)(ws + SZ);             // [Mp][384] = 0.75 SZ
  unsigned short* valbf = (unsigned short*)(ws + SZ + (3 * SZ) / 4); // 0.5 SZ
  unsigned short* attbf = valbf + SZ;                 // 0.5 SZ
  unsigned short* ffbf  = (unsigned short*)(ws + SZ); // [Mp][1024], aliases ^
  unsigned short* posbf = (unsigned short*)(ws + 3 * SZ);      // 0.5 SZ
  unsigned short* qbf   = posbf + SZ;                          // 0.5 SZ
  unsigned short* xbf   = qbf + SZ;                            // 0.5 SZ
  unsigned short* wts   = (unsigned short*)(ws + 4 * SZ + SZ / 2);
  unsigned short* qwT  = wts;                    // [NL][384][256]
  unsigned short* valT = qwT + kNL * 384 * 256;  // [NL][256][256]
  unsigned short* outT = valT + kNL * 256 * 256;
  unsigned short* ff1T = outT + kNL * 256 * 256; // [NL][1024][256]
  unsigned short* ff2T = ff1T + kNL * 1024 * 256;// [NL][256][1024]
  float* qbias = (float*)(ff2T + kNL * 256 * 1024); // [NL][384]
  float* reftab = qbias + kNL * 384;                // [kS][2]

  // --- weight prep + ref table ---
  wconv_k<<<dim3(256 / 32, 256 / 32, kNL), 256, 0, stream>>>(off_w, qwT, 256, 256, 0, 384);
  wconv_k<<<dim3(128 / 32, 256 / 32, kNL), 256, 0, stream>>>(aw_w,  qwT, 256, 128, 256, 384);
  wconv_k<<<dim3(256 / 32, 256 / 32, kNL), 256, 0, stream>>>(val_w, valT, 256, 256, 0, 256);
  wconv_k<<<dim3(256 / 32, 256 / 32, kNL), 256, 0, stream>>>(out_w, outT, 256, 256, 0, 256);
  wconv_k<<<dim3(1024 / 32, 256 / 32, kNL), 256, 0, stream>>>(ff1_w, ff1T, 256, 1024, 0, 1024);
  wconv_k<<<dim3(256 / 32, 1024 / 32, kNL), 256, 0, stream>>>(ff2_w, ff2T, 1024, 256, 0, 256);
  biaspack_k<<<(kNL * 384 + 255) / 256, 256, 0, stream>>>(off_b, aw_b, qbias);
  refxy_k<<<(kS + 255) / 256, 256, 0, stream>>>(reftab);

  // --- build bf16 x, q, pos ---
  const int sides[4]  = {112, 56, 28, 14};
  const int starts[4] = {0, 12544, 15680, 16464};
  for (int l = 0; l < 4; ++l) {
    int HW = sides[l] * sides[l];
    dim3 g((HW + 31) / 32, kD / 32, kB);
    build_xpos_k<<<g, dim3(32, 8), 0, stream>>>(src[l], pos[l], lemb, posbf,
                                                xbf, qbf, HW, starts[l], l);
  }

  const dim3 blk(256);
  for (int i = 0; i < kNL; ++i) {
    // qout = (x+pos) @ [off_w|aw_w] + qbias (fp16)  AND  val = x @ val_w + b
    qvgemm_k<<<dim3(5, kMT64), blk, 0, stream>>>(
        qbf, xbf, qwT + (size_t)i * 384 * 256, valT + (size_t)i * 256 * 256,
        qbias + i * 384, val_b + i * 256, qoutH, valbf);
    // sampling (+softmax fused)
    msdeform_k<<<kM / 8, blk, 0, stream>>>(valbf, qoutH, reftab, attbf);
    // x = LN1(x + attn @ out_w + out_b)  [fused; persistent grid 512]
    hgemmln_k<0, 0><<<kPERS, 512, 0, stream>>>(
        attbf, outT + (size_t)i * 256 * 256, out_b + i * 256, xbf,
        ln1_s + i * kD, ln1_b + i * kD, nullptr, nullptr, xbf, nullptr, 256);
    // ffmid = relu(x @ ff1_w + ff1_b) -> bf16
    hgemm64_k<1, 1><<<dim3(8, kMT64), blk, 0, stream>>>(
        xbf, ff1T + (size_t)i * 1024 * 256, ff1_b + i * 1024, ffbf, 1024, 256);
    // x = LN2(x + ffmid @ ff2_w + ff2_b)  [fused; persistent; last -> d_out]
    if (i < kNL - 1) {
      hgemmln_k<1, 0><<<kPERS, 512, 0, stream>>>(
          ffbf, ff2T + (size_t)i * 256 * 1024, ff2_b + i * 256, xbf,
          ln2_s + i * kD, ln2_b + i * kD, posbf, nullptr, xbf, qbf, 1024);
    } else {
      hgemmln_k<0, 1><<<kPERS, 512, 0, stream>>>(
          ffbf, ff2T + (size_t)i * 256 * 1024, ff2_b + i * 256, xbf,
          ln2_s + i * kD, ln2_b + i * kD, nullptr, (float*)d_out, nullptr,
          nullptr, 1024);
    }
  }

  tail_k<<<1, 64, 0, stream>>>((float*)d_out);
}